// Round 7
// baseline (454.193 us; speedup 1.0000x reference)
//
#include <hip/hip_runtime.h>
#include <hip/hip_bf16.h>
#include <math.h>

#define D_IN 128
#define D_HID 128
#define D_OUT 64
#define BN_EPS 1e-5f
#define SLOPE 0.01f
#define NSCALE 1.8f

typedef __attribute__((ext_vector_type(8))) short short8;
typedef __attribute__((ext_vector_type(4))) float f32x4;

__device__ inline void atomAddF(float* p, float v) {
#if defined(__gfx90a__) || defined(__gfx942__) || defined(__gfx950__)
    unsafeAtomicAdd(p, v);
#else
    atomicAdd(p, v);
#endif
}

__device__ inline ushort f2bf(float f) {  // RNE
    union { float f; uint u; } v; v.f = f;
    uint r = v.u + 0x7fff + ((v.u >> 16) & 1);
    return (ushort)(r >> 16);
}
__device__ inline float bf2f(ushort b) {
    union { uint u; float f; } v; v.u = ((uint)b) << 16;
    return v.f;
}
__device__ inline float bflo(uint u) { return __uint_as_float(u << 16); }
__device__ inline float bfhi(uint u) { return __uint_as_float(u & 0xffff0000u); }

__device__ inline void add8(uint4 v, float a[8]) {
    a[0] += bflo(v.x); a[1] += bfhi(v.x);
    a[2] += bflo(v.y); a[3] += bfhi(v.y);
    a[4] += bflo(v.z); a[5] += bfhi(v.z);
    a[6] += bflo(v.w); a[7] += bfhi(v.w);
}
__device__ inline void fma8(uint4 v, float w, float a[8]) {
    a[0] = fmaf(bflo(v.x), w, a[0]);
    a[1] = fmaf(bfhi(v.x), w, a[1]);
    a[2] = fmaf(bflo(v.y), w, a[2]);
    a[3] = fmaf(bfhi(v.y), w, a[3]);
    a[4] = fmaf(bflo(v.z), w, a[4]);
    a[5] = fmaf(bfhi(v.z), w, a[5]);
    a[6] = fmaf(bflo(v.w), w, a[6]);
    a[7] = fmaf(bfhi(v.w), w, a[7]);
}

__global__ void k_deg(const int* __restrict__ dst, int* __restrict__ deg, int E) {
    int e = blockIdx.x * blockDim.x + threadIdx.x;
    if (e < E) atomicAdd(&deg[dst[e]], 1);
}

// --- scan: rowptr/cursor = exclusive_prefix(deg); dinv = rsqrt(deg+1) ---
__global__ void k_scanA(const int* __restrict__ deg, int* __restrict__ bsum, int n) {
    __shared__ int sh[256];
    int i = blockIdx.x * 256 + threadIdx.x;
    sh[threadIdx.x] = (i < n) ? deg[i] : 0;
    __syncthreads();
    for (int off = 128; off >= 1; off >>= 1) {
        if (threadIdx.x < off) sh[threadIdx.x] += sh[threadIdx.x + off];
        __syncthreads();
    }
    if (threadIdx.x == 0) bsum[blockIdx.x] = sh[0];
}

__global__ void k_scanB(int* __restrict__ bsum, int nb) {  // single block, nb <= 512
    __shared__ int sh[512];
    int v = (threadIdx.x < nb) ? bsum[threadIdx.x] : 0;
    sh[threadIdx.x] = v;
    __syncthreads();
    for (int off = 1; off < 512; off <<= 1) {
        int t = (threadIdx.x >= off) ? sh[threadIdx.x - off] : 0;
        __syncthreads();
        sh[threadIdx.x] += t;
        __syncthreads();
    }
    if (threadIdx.x < nb) bsum[threadIdx.x] = sh[threadIdx.x] - v;  // exclusive
}

__global__ void k_scanC(const int* __restrict__ deg, const int* __restrict__ bsum,
                        int* __restrict__ rowptr, int* __restrict__ cursor,
                        float* __restrict__ dinv, int n) {
    __shared__ int sh[256];
    int i = blockIdx.x * 256 + threadIdx.x;
    int v = (i < n) ? deg[i] : 0;
    sh[threadIdx.x] = v;
    __syncthreads();
    for (int off = 1; off < 256; off <<= 1) {
        int t = (threadIdx.x >= off) ? sh[threadIdx.x - off] : 0;
        __syncthreads();
        sh[threadIdx.x] += t;
        __syncthreads();
    }
    int excl = sh[threadIdx.x] - v + bsum[blockIdx.x];
    if (i < n) {
        rowptr[i] = excl;
        cursor[i] = excl;
        dinv[i] = rsqrtf((float)v + 1.0f);
    }
    if (i == n - 1) rowptr[n] = excl + v;
}

// scatter edges into CSR (by dst): col[p] = src. cursor pre-init'd to rowptr.
__global__ void k_scatter(const int* __restrict__ src, const int* __restrict__ dst,
                          int* __restrict__ cursor, int* __restrict__ col, int E) {
    int e = blockIdx.x * blockDim.x + threadIdx.x;
    if (e >= E) return;
    int p = atomicAdd(&cursor[dst[e]], 1);
    col[p] = src[e];
}

// h_bf = bf16((x @ W1 + b1) * dinv[row]). Split-bf16 MFMA, W1 fragments in LDS.
__global__ __launch_bounds__(256) void k_gemm1_mfma(const float* __restrict__ x,
        const float* __restrict__ W1, const float* __restrict__ b1,
        const float* __restrict__ dinv, ushort* __restrict__ h_bf, int n, int nwt) {
    __shared__ ushort wf[2][4][8][64][8];  // [hi/lo][kt][ct][lane][j] = 64KB
    int t = threadIdx.x;
    for (int i = t; i < 16384; i += 256) {
        int k = i >> 7, nn = i & 127;
        float v = W1[i];
        ushort hi = f2bf(v);
        ushort lo = f2bf(v - bf2f(hi));
        int kt = k >> 5, ct = nn >> 4;
        int lane = ((k >> 3) & 3) * 16 + (nn & 15);
        int j = k & 7;
        wf[0][kt][ct][lane][j] = hi;
        wf[1][kt][ct][lane][j] = lo;
    }
    __syncthreads();
    int wid = t >> 6, lane = t & 63;
    int lrow = lane & 15, lkg = lane >> 4;
    float bias[8];
#pragma unroll
    for (int ct = 0; ct < 8; ++ct) bias[ct] = b1[ct * 16 + lrow];
    int stride = gridDim.x * 4;
    for (int wt = blockIdx.x * 4 + wid; wt < nwt; wt += stride) {
        size_t r0 = (size_t)wt * 16;
        int rr = (int)r0 + lrow;
        if (rr >= n) rr = n - 1;
        short8 ah[4], al[4];
#pragma unroll
        for (int kt = 0; kt < 4; ++kt) {
            const float* p = x + (size_t)rr * 128 + kt * 32 + lkg * 8;
            float va[8];
            *(f32x4*)&va[0] = *(const f32x4*)p;
            *(f32x4*)&va[4] = *(const f32x4*)(p + 4);
#pragma unroll
            for (int j = 0; j < 8; ++j) {
                ushort hb = f2bf(va[j]);
                ah[kt][j] = (short)hb;
                al[kt][j] = (short)f2bf(va[j] - bf2f(hb));
            }
        }
        f32x4 acc[8];
#pragma unroll
        for (int ct = 0; ct < 8; ++ct) {
            float bb = bias[ct];
            acc[ct][0] = bb; acc[ct][1] = bb; acc[ct][2] = bb; acc[ct][3] = bb;
        }
#pragma unroll
        for (int kt = 0; kt < 4; ++kt) {
#pragma unroll
            for (int ct = 0; ct < 8; ++ct) {
                short8 wh = *(const short8*)&wf[0][kt][ct][lane][0];
                short8 wl = *(const short8*)&wf[1][kt][ct][lane][0];
                acc[ct] = __builtin_amdgcn_mfma_f32_16x16x32_bf16(ah[kt], wh, acc[ct], 0, 0, 0);
                acc[ct] = __builtin_amdgcn_mfma_f32_16x16x32_bf16(al[kt], wh, acc[ct], 0, 0, 0);
                acc[ct] = __builtin_amdgcn_mfma_f32_16x16x32_bf16(ah[kt], wl, acc[ct], 0, 0, 0);
            }
        }
#pragma unroll
        for (int j = 0; j < 4; ++j) {
            int row = (int)r0 + lkg * 4 + j;
            if (row < n) {
                float dr = dinv[row];
#pragma unroll
                for (int ct = 0; ct < 8; ++ct)
                    h_bf[(size_t)row * 128 + ct * 16 + lrow] = f2bf(acc[ct][j] * dr);
            }
        }
    }
}

// pull SpMM1, weightless: agg[d] = dinv[d]*(sum_in h'[src] + h'[d]).
// quarter-wave (16 lanes x uint4 = 256B row), 16 edges in flight. Fused BN stats.
__global__ __launch_bounds__(512) void k_spmm1_csr(const int* __restrict__ rowptr,
        const int* __restrict__ col, const uint4* __restrict__ hb4,
        const float* __restrict__ dinv, uint4* __restrict__ agg_bf,
        float* __restrict__ accum, int n) {
    __shared__ float red[8][16][8];
    int t = threadIdx.x;
    int wid = t >> 6, lane = t & 63;
    int q = lane >> 4, g = lane & 15;
    int gw = blockIdx.x * 8 + wid;
    int nw = gridDim.x * 8;
    float sx[8], sq[8];
#pragma unroll
    for (int j = 0; j < 8; ++j) { sx[j] = 0.f; sq[j] = 0.f; }
    for (int node = gw; node < n; node += nw) {
        int beg = rowptr[node], end = rowptr[node + 1];
        float a[8];
#pragma unroll
        for (int j = 0; j < 8; ++j) a[j] = 0.f;
        if (q == 0) add8(hb4[(size_t)node * 16 + g], a);  // self-loop
        int p = beg;
        for (; p + 16 <= end; p += 16) {
            int c0 = col[p + q], c1 = col[p + 4 + q];
            int c2 = col[p + 8 + q], c3 = col[p + 12 + q];
            uint4 v0 = hb4[(size_t)c0 * 16 + g];
            uint4 v1 = hb4[(size_t)c1 * 16 + g];
            uint4 v2 = hb4[(size_t)c2 * 16 + g];
            uint4 v3 = hb4[(size_t)c3 * 16 + g];
            add8(v0, a); add8(v1, a); add8(v2, a); add8(v3, a);
        }
        if (p + 8 <= end) {
            int c0 = col[p + q], c1 = col[p + 4 + q];
            uint4 v0 = hb4[(size_t)c0 * 16 + g];
            uint4 v1 = hb4[(size_t)c1 * 16 + g];
            add8(v0, a); add8(v1, a);
            p += 8;
        }
        if (p < end) {
            int i0 = p + q, i1 = p + 4 + q;
            int c0 = col[i0 < end ? i0 : end - 1];
            int c1 = col[i1 < end ? i1 : end - 1];
            float w0 = (i0 < end) ? 1.f : 0.f;
            float w1 = (i1 < end) ? 1.f : 0.f;
            fma8(hb4[(size_t)c0 * 16 + g], w0, a);
            fma8(hb4[(size_t)c1 * 16 + g], w1, a);
        }
#pragma unroll
        for (int j = 0; j < 8; ++j) {
            a[j] += __shfl_xor(a[j], 16, 64);
            a[j] += __shfl_xor(a[j], 32, 64);
        }
        if (q == 0) {
            float di = dinv[node];
#pragma unroll
            for (int j = 0; j < 8; ++j) a[j] *= di;
            uint4 pk;
            pk.x = ((uint)f2bf(a[1]) << 16) | (uint)f2bf(a[0]);
            pk.y = ((uint)f2bf(a[3]) << 16) | (uint)f2bf(a[2]);
            pk.z = ((uint)f2bf(a[5]) << 16) | (uint)f2bf(a[4]);
            pk.w = ((uint)f2bf(a[7]) << 16) | (uint)f2bf(a[6]);
            agg_bf[(size_t)node * 16 + g] = pk;
#pragma unroll
            for (int j = 0; j < 8; ++j) {
                sx[j] += a[j];
                sq[j] = fmaf(a[j], a[j], sq[j]);
            }
        }
    }
    // block reduce stats: col = 8g + j = t for t < 128
    if (q == 0) {
#pragma unroll
        for (int j = 0; j < 8; ++j) red[wid][g][j] = sx[j];
    }
    __syncthreads();
    if (t < 128) {
        float v = 0.f;
        for (int w = 0; w < 8; ++w) v += red[w][t >> 3][t & 7];
        atomAddF(&accum[t], v);
    }
    __syncthreads();
    if (q == 0) {
#pragma unroll
        for (int j = 0; j < 8; ++j) red[wid][g][j] = sq[j];
    }
    __syncthreads();
    if (t < 128) {
        float v = 0.f;
        for (int w = 0; w < 8; ++w) v += red[w][t >> 3][t & 7];
        atomAddF(&accum[128 + t], v);
    }
}

__global__ void k_bnfinal(float* __restrict__ accum, const float* __restrict__ gamma,
        const float* __restrict__ beta, float inv_n) {
    int c = threadIdx.x;
    float mean = accum[c] * inv_n;
    float var = accum[D_HID + c] * inv_n - mean * mean;
    float sc = gamma[c] * rsqrtf(var + BN_EPS);
    accum[c] = sc;
    accum[D_HID + c] = beta[c] - mean * sc;
}

// l_ext = [ bf16(l*dinv) | bf16(l*s*dinv) ], l = lrelu(bn(agg)) @ Wmu + bmu,
// s = 1.8/max(||l||,1e-12)
__global__ __launch_bounds__(256) void k_gemm2_mfma(const ushort* __restrict__ agg_bf,
        const float* __restrict__ Wmu, const float* __restrict__ bmu,
        const float* __restrict__ accum, const float* __restrict__ dinv,
        ushort* __restrict__ l_ext, int n, int nwt) {
    __shared__ ushort wf[2][4][4][64][8];  // 32KB
    __shared__ float scs[D_HID], shs[D_HID];
    int t = threadIdx.x;
    for (int i = t; i < 8192; i += 256) {
        int k = i >> 6, nn = i & 63;
        float v = Wmu[i];
        ushort hi = f2bf(v);
        ushort lo = f2bf(v - bf2f(hi));
        int kt = k >> 5, ct = nn >> 4;
        int lane = ((k >> 3) & 3) * 16 + (nn & 15);
        int j = k & 7;
        wf[0][kt][ct][lane][j] = hi;
        wf[1][kt][ct][lane][j] = lo;
    }
    for (int i = t; i < D_HID; i += 256) {
        scs[i] = accum[i];
        shs[i] = accum[D_HID + i];
    }
    __syncthreads();
    int wid = t >> 6, lane = t & 63;
    int lrow = lane & 15, lkg = lane >> 4;
    float bias[4];
#pragma unroll
    for (int ct = 0; ct < 4; ++ct) bias[ct] = bmu[ct * 16 + lrow];
    int stride = gridDim.x * 4;
    for (int wt = blockIdx.x * 4 + wid; wt < nwt; wt += stride) {
        size_t r0 = (size_t)wt * 16;
        int rr = (int)r0 + lrow;
        if (rr >= n) rr = n - 1;
        short8 ah[4], al[4];
#pragma unroll
        for (int kt = 0; kt < 4; ++kt) {
            const ushort* p = agg_bf + (size_t)rr * 128 + kt * 32 + lkg * 8;
            short8 raw = *(const short8*)p;
#pragma unroll
            for (int j = 0; j < 8; ++j) {
                int k = kt * 32 + lkg * 8 + j;
                float v = bf2f((ushort)raw[j]) * scs[k] + shs[k];
                v = v > 0.f ? v : SLOPE * v;
                ushort hb = f2bf(v);
                ah[kt][j] = (short)hb;
                al[kt][j] = (short)f2bf(v - bf2f(hb));
            }
        }
        f32x4 acc[4];
#pragma unroll
        for (int ct = 0; ct < 4; ++ct) {
            float bb = bias[ct];
            acc[ct][0] = bb; acc[ct][1] = bb; acc[ct][2] = bb; acc[ct][3] = bb;
        }
#pragma unroll
        for (int kt = 0; kt < 4; ++kt) {
#pragma unroll
            for (int ct = 0; ct < 4; ++ct) {
                short8 wh = *(const short8*)&wf[0][kt][ct][lane][0];
                short8 wl = *(const short8*)&wf[1][kt][ct][lane][0];
                acc[ct] = __builtin_amdgcn_mfma_f32_16x16x32_bf16(ah[kt], wh, acc[ct], 0, 0, 0);
                acc[ct] = __builtin_amdgcn_mfma_f32_16x16x32_bf16(al[kt], wh, acc[ct], 0, 0, 0);
                acc[ct] = __builtin_amdgcn_mfma_f32_16x16x32_bf16(ah[kt], wl, acc[ct], 0, 0, 0);
            }
        }
#pragma unroll
        for (int j = 0; j < 4; ++j) {
            float ss = acc[0][j] * acc[0][j];
#pragma unroll
            for (int ct = 1; ct < 4; ++ct) ss = fmaf(acc[ct][j], acc[ct][j], ss);
            ss += __shfl_xor(ss, 1, 64);
            ss += __shfl_xor(ss, 2, 64);
            ss += __shfl_xor(ss, 4, 64);
            ss += __shfl_xor(ss, 8, 64);
            float srow = NSCALE / fmaxf(sqrtf(ss), 1e-12f);
            int row = (int)r0 + lkg * 4 + j;
            if (row < n) {
                float dr = dinv[row];
#pragma unroll
                for (int ct = 0; ct < 4; ++ct) {
                    float lv = acc[ct][j];
                    l_ext[(size_t)row * 128 + ct * 16 + lrow] = f2bf(lv * dr);
                    l_ext[(size_t)row * 128 + 64 + ct * 16 + lrow] = f2bf(lv * srow * dr);
                }
            }
        }
    }
}

// pull SpMM2 over l_ext (256B rows: [l' | l'*s]), weightless, quarter-wave,
// fused reparam. After combine+di scale, lane g<8 = mu cols, g>=8 = logstd cols.
__global__ __launch_bounds__(512) void k_spmm2_csr(const int* __restrict__ rowptr,
        const int* __restrict__ col, const uint4* __restrict__ le4,
        const float* __restrict__ dinv, const float* __restrict__ noise,
        float* __restrict__ mu, float* __restrict__ lsd, float* __restrict__ zeta,
        int n) {
    int node = blockIdx.x * 8 + ((int)threadIdx.x >> 6);
    if (node >= n) return;
    int lane = threadIdx.x & 63;
    int q = lane >> 4, g = lane & 15;
    int beg = rowptr[node], end = rowptr[node + 1];
    float a[8];
#pragma unroll
    for (int j = 0; j < 8; ++j) a[j] = 0.f;
    if (q == 0) add8(le4[(size_t)node * 16 + g], a);  // self-loop
    int p = beg;
    for (; p + 16 <= end; p += 16) {
        int c0 = col[p + q], c1 = col[p + 4 + q];
        int c2 = col[p + 8 + q], c3 = col[p + 12 + q];
        uint4 v0 = le4[(size_t)c0 * 16 + g];
        uint4 v1 = le4[(size_t)c1 * 16 + g];
        uint4 v2 = le4[(size_t)c2 * 16 + g];
        uint4 v3 = le4[(size_t)c3 * 16 + g];
        add8(v0, a); add8(v1, a); add8(v2, a); add8(v3, a);
    }
    if (p + 8 <= end) {
        int c0 = col[p + q], c1 = col[p + 4 + q];
        uint4 v0 = le4[(size_t)c0 * 16 + g];
        uint4 v1 = le4[(size_t)c1 * 16 + g];
        add8(v0, a); add8(v1, a);
        p += 8;
    }
    if (p < end) {
        int i0 = p + q, i1 = p + 4 + q;
        int c0 = col[i0 < end ? i0 : end - 1];
        int c1 = col[i1 < end ? i1 : end - 1];
        float w0 = (i0 < end) ? 1.f : 0.f;
        float w1 = (i1 < end) ? 1.f : 0.f;
        fma8(le4[(size_t)c0 * 16 + g], w0, a);
        fma8(le4[(size_t)c1 * 16 + g], w1, a);
    }
#pragma unroll
    for (int j = 0; j < 8; ++j) {
        a[j] += __shfl_xor(a[j], 16, 64);
        a[j] += __shfl_xor(a[j], 32, 64);
    }
    if (q == 0) {
        float di = dinv[node];
#pragma unroll
        for (int j = 0; j < 8; ++j) a[j] *= di;
        float b[8];
#pragma unroll
        for (int j = 0; j < 8; ++j) b[j] = __shfl_xor(a[j], 8, 64);
        if (g < 8) {
            size_t idx = (size_t)node * 64 + g * 8;
            f32x4 m0 = {a[0], a[1], a[2], a[3]};
            f32x4 m1 = {a[4], a[5], a[6], a[7]};
            *(f32x4*)(mu + idx) = m0;
            *(f32x4*)(mu + idx + 4) = m1;
            f32x4 n0 = *(const f32x4*)(noise + idx);
            f32x4 n1 = *(const f32x4*)(noise + idx + 4);
            f32x4 z0, z1;
            z0[0] = a[0] + n0[0] * expf(b[0]);
            z0[1] = a[1] + n0[1] * expf(b[1]);
            z0[2] = a[2] + n0[2] * expf(b[2]);
            z0[3] = a[3] + n0[3] * expf(b[3]);
            z1[0] = a[4] + n1[0] * expf(b[4]);
            z1[1] = a[5] + n1[1] * expf(b[5]);
            z1[2] = a[6] + n1[2] * expf(b[6]);
            z1[3] = a[7] + n1[3] * expf(b[7]);
            *(f32x4*)(zeta + idx) = z0;
            *(f32x4*)(zeta + idx + 4) = z1;
        } else {
            size_t idx = (size_t)node * 64 + (g - 8) * 8;
            f32x4 l0 = {a[0], a[1], a[2], a[3]};
            f32x4 l1 = {a[4], a[5], a[6], a[7]};
            *(f32x4*)(lsd + idx) = l0;
            *(f32x4*)(lsd + idx + 4) = l1;
        }
    }
}

extern "C" void kernel_launch(void* const* d_in, const int* in_sizes, int n_in,
                              void* d_out, int out_size, void* d_ws, size_t ws_size,
                              hipStream_t stream) {
    const float* x     = (const float*)d_in[0];
    const int*   esrc  = (const int*)d_in[1];
    const int*   edst  = (const int*)d_in[2];
    const float* W1    = (const float*)d_in[3];
    const float* b1    = (const float*)d_in[4];
    const float* gamma = (const float*)d_in[5];
    const float* beta  = (const float*)d_in[6];
    const float* Wmu   = (const float*)d_in[7];
    const float* bmu   = (const float*)d_in[8];
    const float* noise = (const float*)d_in[9];
    int N = in_sizes[0] / D_IN;
    int E = in_sizes[1];
    int nb = (N + 255) / 256;
    int nwt = (N + 15) / 16;

    float* out  = (float*)d_out;
    float* mu   = out;
    float* lsd  = out + (size_t)N * D_OUT;
    float* zeta = out + 2 * (size_t)N * D_OUT;

    char* ws = (char*)d_ws;
    size_t off = 0;
    auto alloc = [&](size_t bytes) {
        void* p = ws + off;
        off += (bytes + 255) & ~(size_t)255;
        return p;
    };
    int* deg      = (int*)alloc((size_t)N * 4);
    float* accum  = (float*)alloc(1024);
    size_t zbytes = off;  // deg + accum zeroed
    int* cursor   = (int*)alloc((size_t)N * 4);   // init'd by scanC
    float* dinv   = (float*)alloc((size_t)N * 4);
    int* rowptr   = (int*)alloc(((size_t)N + 1) * 4);
    int* bsum     = (int*)alloc(2048);
    int* col      = (int*)alloc((size_t)E * 4);
    ushort* h_bf  = (ushort*)alloc((size_t)N * D_HID * 2);
    uint4* agg_bf = (uint4*)alloc((size_t)N * D_HID * 2);
    ushort* l_ext = (ushort*)alloc((size_t)N * 128 * 2);

    hipMemsetAsync(d_ws, 0, zbytes, stream);

    k_deg<<<(E + 255) / 256, 256, 0, stream>>>(edst, deg, E);
    k_scanA<<<nb, 256, 0, stream>>>(deg, bsum, N);
    k_scanB<<<1, 512, 0, stream>>>(bsum, nb);
    k_scanC<<<nb, 256, 0, stream>>>(deg, bsum, rowptr, cursor, dinv, N);
    k_scatter<<<(E + 255) / 256, 256, 0, stream>>>(esrc, edst, cursor, col, E);
    k_gemm1_mfma<<<512, 256, 0, stream>>>(x, W1, b1, dinv, h_bf, N, nwt);
    k_spmm1_csr<<<1024, 512, 0, stream>>>(rowptr, col, (const uint4*)h_bf, dinv, agg_bf, accum, N);
    k_bnfinal<<<1, 128, 0, stream>>>(accum, gamma, beta, 1.0f / (float)N);
    k_gemm2_mfma<<<512, 256, 0, stream>>>((const ushort*)agg_bf, Wmu, bmu, accum, dinv, l_ext, N, nwt);
    k_spmm2_csr<<<(N + 7) / 8, 512, 0, stream>>>(rowptr, col, (const uint4*)l_ext, dinv, noise, mu, lsd, zeta, N);
}

// Round 8
// 320.396 us; speedup vs baseline: 1.4176x; 1.4176x over previous
//
#include <hip/hip_runtime.h>
#include <hip/hip_bf16.h>
#include <math.h>

#define D_IN 128
#define D_HID 128
#define D_OUT 64
#define BN_EPS 1e-5f
#define SLOPE 0.01f
#define NSCALE 1.8f

#define BSH 8          // nodes per bucket = 256
#define NB 256
#define T1 4096        // edges per partition tile
#define COLCAP 8192    // LDS col staging per bucket (mean cnt ~4092)

typedef __attribute__((ext_vector_type(8))) short short8;
typedef __attribute__((ext_vector_type(4))) float f32x4;

__device__ inline void atomAddF(float* p, float v) {
#if defined(__gfx90a__) || defined(__gfx942__) || defined(__gfx950__)
    unsafeAtomicAdd(p, v);
#else
    atomicAdd(p, v);
#endif
}

__device__ inline ushort f2bf(float f) {  // RNE
    union { float f; uint u; } v; v.f = f;
    uint r = v.u + 0x7fff + ((v.u >> 16) & 1);
    return (ushort)(r >> 16);
}
__device__ inline float bf2f(ushort b) {
    union { uint u; float f; } v; v.u = ((uint)b) << 16;
    return v.f;
}
__device__ inline float bflo(uint u) { return __uint_as_float(u << 16); }
__device__ inline float bfhi(uint u) { return __uint_as_float(u & 0xffff0000u); }

__device__ inline void add8(uint4 v, float a[8]) {
    a[0] += bflo(v.x); a[1] += bfhi(v.x);
    a[2] += bflo(v.y); a[3] += bfhi(v.y);
    a[4] += bflo(v.z); a[5] += bfhi(v.z);
    a[6] += bflo(v.w); a[7] += bfhi(v.w);
}
__device__ inline void fma8(uint4 v, float w, float a[8]) {
    a[0] = fmaf(bflo(v.x), w, a[0]);
    a[1] = fmaf(bfhi(v.x), w, a[1]);
    a[2] = fmaf(bflo(v.y), w, a[2]);
    a[3] = fmaf(bfhi(v.y), w, a[3]);
    a[4] = fmaf(bflo(v.z), w, a[4]);
    a[5] = fmaf(bfhi(v.z), w, a[5]);
    a[6] = fmaf(bflo(v.w), w, a[6]);
    a[7] = fmaf(bfhi(v.w), w, a[7]);
}

// ---- bucket histogram (LDS-staged) -------------------------------------
__global__ __launch_bounds__(256) void k_bhist(const int* __restrict__ dst,
        int* __restrict__ bcnt, int E, int B) {
    __shared__ int h[512];
    for (int i = threadIdx.x; i < 512; i += 256) h[i] = 0;
    __syncthreads();
    int beg = blockIdx.x * T1;
    int end = min(beg + T1, E);
    for (int e = beg + threadIdx.x; e < end; e += 256)
        atomicAdd(&h[dst[e] >> BSH], 1);
    __syncthreads();
    for (int i = threadIdx.x; i < B; i += 256)
        if (h[i]) atomicAdd(&bcnt[i], h[i]);
}

// ---- bucket base scan (single block, B <= 512) -------------------------
__global__ __launch_bounds__(512) void k_bscan(const int* __restrict__ bcnt,
        int* __restrict__ bbase, int* __restrict__ tailE, int B) {
    __shared__ int sh[512];
    int t = threadIdx.x;
    int v = (t < B) ? bcnt[t] : 0;
    sh[t] = v;
    __syncthreads();
    for (int o = 1; o < 512; o <<= 1) {
        int u = (t >= o) ? sh[t - o] : 0;
        __syncthreads();
        sh[t] += u;
        __syncthreads();
    }
    int excl = sh[t] - v;
    if (t < B) { bbase[t] = excl; tailE[t] = excl; }
    if (t == B - 1) bbase[B] = excl + v;
}

// ---- partition edges into bucket regions (LDS reorder, coalesced out) --
__global__ __launch_bounds__(256) void k_part(const int* __restrict__ src,
        const int* __restrict__ dst, int* __restrict__ tailE,
        int2* __restrict__ ep, int E, int B) {
    __shared__ int h[512], off[512], gb[512], cur[512];
    __shared__ int ps[256];
    __shared__ int2 ro[T1];
    int tid = threadIdx.x;
    for (int i = tid; i < 512; i += 256) h[i] = 0;
    __syncthreads();
    int beg = blockIdx.x * T1;
    int cnt = min(T1, E - beg);
    int s[16], d[16];
#pragma unroll
    for (int k = 0; k < 16; ++k) {
        int e = beg + tid + k * 256;
        if (e < E) {
            s[k] = src[e]; d[k] = dst[e];
            atomicAdd(&h[d[k] >> BSH], 1);
        } else d[k] = -1;
    }
    __syncthreads();
    // pair scan: thread t owns bins 2t, 2t+1
    int pa = h[2 * tid], pb = h[2 * tid + 1];
    ps[tid] = pa + pb;
    __syncthreads();
    int vv = ps[tid];
    for (int o = 1; o < 256; o <<= 1) {
        int u = (tid >= o) ? ps[tid - o] : 0;
        __syncthreads();
        ps[tid] += u;
        __syncthreads();
    }
    int excl = ps[tid] - vv;
    off[2 * tid] = excl;       off[2 * tid + 1] = excl + pa;
    cur[2 * tid] = excl;       cur[2 * tid + 1] = excl + pa;
    if (2 * tid < B && pa > 0)      gb[2 * tid] = atomicAdd(&tailE[2 * tid], pa);
    if (2 * tid + 1 < B && pb > 0)  gb[2 * tid + 1] = atomicAdd(&tailE[2 * tid + 1], pb);
    __syncthreads();
#pragma unroll
    for (int k = 0; k < 16; ++k) {
        if (d[k] >= 0) {
            int b = d[k] >> BSH;
            int p = atomicAdd(&cur[b], 1);
            ro[p] = make_int2(s[k], d[k]);
        }
    }
    __syncthreads();
    for (int i = tid; i < cnt; i += 256) {
        int2 e = ro[i];
        int b = e.y >> BSH;
        ep[gb[b] + (i - off[b])] = e;
    }
}

// ---- per-bucket: deg/rowptr/dinv + CSR col build in LDS ----------------
__global__ __launch_bounds__(256) void k_csr(const int2* __restrict__ ep,
        const int* __restrict__ bbase, int* __restrict__ rowptr,
        float* __restrict__ dinv, int* __restrict__ col, int n, int B) {
    int b = blockIdx.x;
    int lo = b << BSH;
    int hi = min(lo + NB, n);
    int nn = hi - lo;
    int ebeg = bbase[b], eend = bbase[b + 1], cnt = eend - ebeg;
    __shared__ int h[NB], pfx[NB], cur[NB];
    __shared__ int colbuf[COLCAP];
    int tid = threadIdx.x;
    if (tid < NB) h[tid] = 0;
    __syncthreads();
    for (int i = tid; i < cnt; i += 256)
        atomicAdd(&h[ep[ebeg + i].y - lo], 1);
    __syncthreads();
    int v = (tid < nn) ? h[tid] : 0;
    pfx[tid] = v;
    __syncthreads();
    for (int o = 1; o < 256; o <<= 1) {
        int u = (tid >= o) ? pfx[tid - o] : 0;
        __syncthreads();
        pfx[tid] += u;
        __syncthreads();
    }
    int excl = pfx[tid] - v;
    if (tid < nn) {
        rowptr[lo + tid] = ebeg + excl;
        dinv[lo + tid] = rsqrtf((float)v + 1.0f);
        cur[tid] = excl;
    }
    if (b == B - 1 && tid == 0) rowptr[n] = eend;
    __syncthreads();
    if (cnt <= COLCAP) {
        for (int i = tid; i < cnt; i += 256) {
            int2 e = ep[ebeg + i];
            int p = atomicAdd(&cur[e.y - lo], 1);
            colbuf[p] = e.x;
        }
        __syncthreads();
        for (int i = tid; i < cnt; i += 256) col[ebeg + i] = colbuf[i];
    } else {  // safety fallback (never taken for this input)
        for (int i = tid; i < cnt; i += 256) {
            int2 e = ep[ebeg + i];
            int p = atomicAdd(&cur[e.y - lo], 1);
            col[ebeg + p] = e.x;
        }
    }
}

// h_bf = bf16((x @ W1 + b1) * dinv[row]). Split-bf16 MFMA, W1 fragments in LDS.
__global__ __launch_bounds__(256) void k_gemm1_mfma(const float* __restrict__ x,
        const float* __restrict__ W1, const float* __restrict__ b1,
        const float* __restrict__ dinv, ushort* __restrict__ h_bf, int n, int nwt) {
    __shared__ ushort wf[2][4][8][64][8];  // 64KB
    int t = threadIdx.x;
    for (int i = t; i < 16384; i += 256) {
        int k = i >> 7, nn = i & 127;
        float v = W1[i];
        ushort hi = f2bf(v);
        ushort lo = f2bf(v - bf2f(hi));
        int kt = k >> 5, ct = nn >> 4;
        int lane = ((k >> 3) & 3) * 16 + (nn & 15);
        int j = k & 7;
        wf[0][kt][ct][lane][j] = hi;
        wf[1][kt][ct][lane][j] = lo;
    }
    __syncthreads();
    int wid = t >> 6, lane = t & 63;
    int lrow = lane & 15, lkg = lane >> 4;
    float bias[8];
#pragma unroll
    for (int ct = 0; ct < 8; ++ct) bias[ct] = b1[ct * 16 + lrow];
    int stride = gridDim.x * 4;
    for (int wt = blockIdx.x * 4 + wid; wt < nwt; wt += stride) {
        size_t r0 = (size_t)wt * 16;
        int rr = (int)r0 + lrow;
        if (rr >= n) rr = n - 1;
        short8 ah[4], al[4];
#pragma unroll
        for (int kt = 0; kt < 4; ++kt) {
            const float* p = x + (size_t)rr * 128 + kt * 32 + lkg * 8;
            float va[8];
            *(f32x4*)&va[0] = *(const f32x4*)p;
            *(f32x4*)&va[4] = *(const f32x4*)(p + 4);
#pragma unroll
            for (int j = 0; j < 8; ++j) {
                ushort hb = f2bf(va[j]);
                ah[kt][j] = (short)hb;
                al[kt][j] = (short)f2bf(va[j] - bf2f(hb));
            }
        }
        f32x4 acc[8];
#pragma unroll
        for (int ct = 0; ct < 8; ++ct) {
            float bb = bias[ct];
            acc[ct][0] = bb; acc[ct][1] = bb; acc[ct][2] = bb; acc[ct][3] = bb;
        }
#pragma unroll
        for (int kt = 0; kt < 4; ++kt) {
#pragma unroll
            for (int ct = 0; ct < 8; ++ct) {
                short8 wh = *(const short8*)&wf[0][kt][ct][lane][0];
                short8 wl = *(const short8*)&wf[1][kt][ct][lane][0];
                acc[ct] = __builtin_amdgcn_mfma_f32_16x16x32_bf16(ah[kt], wh, acc[ct], 0, 0, 0);
                acc[ct] = __builtin_amdgcn_mfma_f32_16x16x32_bf16(al[kt], wh, acc[ct], 0, 0, 0);
                acc[ct] = __builtin_amdgcn_mfma_f32_16x16x32_bf16(ah[kt], wl, acc[ct], 0, 0, 0);
            }
        }
#pragma unroll
        for (int j = 0; j < 4; ++j) {
            int row = (int)r0 + lkg * 4 + j;
            if (row < n) {
                float dr = dinv[row];
#pragma unroll
                for (int ct = 0; ct < 8; ++ct)
                    h_bf[(size_t)row * 128 + ct * 16 + lrow] = f2bf(acc[ct][j] * dr);
            }
        }
    }
}

// pull SpMM1, weightless: agg[d] = dinv[d]*(sum_in h'[src] + h'[d]).
__global__ __launch_bounds__(512) void k_spmm1_csr(const int* __restrict__ rowptr,
        const int* __restrict__ col, const uint4* __restrict__ hb4,
        const float* __restrict__ dinv, uint4* __restrict__ agg_bf,
        float* __restrict__ accum, int n) {
    __shared__ float red[8][16][8];
    int t = threadIdx.x;
    int wid = t >> 6, lane = t & 63;
    int q = lane >> 4, g = lane & 15;
    int gw = blockIdx.x * 8 + wid;
    int nw = gridDim.x * 8;
    float sx[8], sq[8];
#pragma unroll
    for (int j = 0; j < 8; ++j) { sx[j] = 0.f; sq[j] = 0.f; }
    for (int node = gw; node < n; node += nw) {
        int beg = rowptr[node], end = rowptr[node + 1];
        float a[8];
#pragma unroll
        for (int j = 0; j < 8; ++j) a[j] = 0.f;
        if (q == 0) add8(hb4[(size_t)node * 16 + g], a);  // self-loop
        int p = beg;
        for (; p + 16 <= end; p += 16) {
            int c0 = col[p + q], c1 = col[p + 4 + q];
            int c2 = col[p + 8 + q], c3 = col[p + 12 + q];
            uint4 v0 = hb4[(size_t)c0 * 16 + g];
            uint4 v1 = hb4[(size_t)c1 * 16 + g];
            uint4 v2 = hb4[(size_t)c2 * 16 + g];
            uint4 v3 = hb4[(size_t)c3 * 16 + g];
            add8(v0, a); add8(v1, a); add8(v2, a); add8(v3, a);
        }
        if (p + 8 <= end) {
            int c0 = col[p + q], c1 = col[p + 4 + q];
            uint4 v0 = hb4[(size_t)c0 * 16 + g];
            uint4 v1 = hb4[(size_t)c1 * 16 + g];
            add8(v0, a); add8(v1, a);
            p += 8;
        }
        if (p < end) {
            int i0 = p + q, i1 = p + 4 + q;
            int c0 = col[i0 < end ? i0 : end - 1];
            int c1 = col[i1 < end ? i1 : end - 1];
            float w0 = (i0 < end) ? 1.f : 0.f;
            float w1 = (i1 < end) ? 1.f : 0.f;
            fma8(hb4[(size_t)c0 * 16 + g], w0, a);
            fma8(hb4[(size_t)c1 * 16 + g], w1, a);
        }
#pragma unroll
        for (int j = 0; j < 8; ++j) {
            a[j] += __shfl_xor(a[j], 16, 64);
            a[j] += __shfl_xor(a[j], 32, 64);
        }
        if (q == 0) {
            float di = dinv[node];
#pragma unroll
            for (int j = 0; j < 8; ++j) a[j] *= di;
            uint4 pk;
            pk.x = ((uint)f2bf(a[1]) << 16) | (uint)f2bf(a[0]);
            pk.y = ((uint)f2bf(a[3]) << 16) | (uint)f2bf(a[2]);
            pk.z = ((uint)f2bf(a[5]) << 16) | (uint)f2bf(a[4]);
            pk.w = ((uint)f2bf(a[7]) << 16) | (uint)f2bf(a[6]);
            agg_bf[(size_t)node * 16 + g] = pk;
#pragma unroll
            for (int j = 0; j < 8; ++j) {
                sx[j] += a[j];
                sq[j] = fmaf(a[j], a[j], sq[j]);
            }
        }
    }
    if (q == 0) {
#pragma unroll
        for (int j = 0; j < 8; ++j) red[wid][g][j] = sx[j];
    }
    __syncthreads();
    if (t < 128) {
        float v = 0.f;
        for (int w = 0; w < 8; ++w) v += red[w][t >> 3][t & 7];
        atomAddF(&accum[t], v);
    }
    __syncthreads();
    if (q == 0) {
#pragma unroll
        for (int j = 0; j < 8; ++j) red[wid][g][j] = sq[j];
    }
    __syncthreads();
    if (t < 128) {
        float v = 0.f;
        for (int w = 0; w < 8; ++w) v += red[w][t >> 3][t & 7];
        atomAddF(&accum[128 + t], v);
    }
}

__global__ void k_bnfinal(float* __restrict__ accum, const float* __restrict__ gamma,
        const float* __restrict__ beta, float inv_n) {
    int c = threadIdx.x;
    float mean = accum[c] * inv_n;
    float var = accum[D_HID + c] * inv_n - mean * mean;
    float sc = gamma[c] * rsqrtf(var + BN_EPS);
    accum[c] = sc;
    accum[D_HID + c] = beta[c] - mean * sc;
}

// l_ext = [ bf16(l*dinv) | bf16(l*s*dinv) ], l = lrelu(bn(agg)) @ Wmu + bmu
__global__ __launch_bounds__(256) void k_gemm2_mfma(const ushort* __restrict__ agg_bf,
        const float* __restrict__ Wmu, const float* __restrict__ bmu,
        const float* __restrict__ accum, const float* __restrict__ dinv,
        ushort* __restrict__ l_ext, int n, int nwt) {
    __shared__ ushort wf[2][4][4][64][8];  // 32KB
    __shared__ float scs[D_HID], shs[D_HID];
    int t = threadIdx.x;
    for (int i = t; i < 8192; i += 256) {
        int k = i >> 6, nn = i & 63;
        float v = Wmu[i];
        ushort hi = f2bf(v);
        ushort lo = f2bf(v - bf2f(hi));
        int kt = k >> 5, ct = nn >> 4;
        int lane = ((k >> 3) & 3) * 16 + (nn & 15);
        int j = k & 7;
        wf[0][kt][ct][lane][j] = hi;
        wf[1][kt][ct][lane][j] = lo;
    }
    for (int i = t; i < D_HID; i += 256) {
        scs[i] = accum[i];
        shs[i] = accum[D_HID + i];
    }
    __syncthreads();
    int wid = t >> 6, lane = t & 63;
    int lrow = lane & 15, lkg = lane >> 4;
    float bias[4];
#pragma unroll
    for (int ct = 0; ct < 4; ++ct) bias[ct] = bmu[ct * 16 + lrow];
    int stride = gridDim.x * 4;
    for (int wt = blockIdx.x * 4 + wid; wt < nwt; wt += stride) {
        size_t r0 = (size_t)wt * 16;
        int rr = (int)r0 + lrow;
        if (rr >= n) rr = n - 1;
        short8 ah[4], al[4];
#pragma unroll
        for (int kt = 0; kt < 4; ++kt) {
            const ushort* p = agg_bf + (size_t)rr * 128 + kt * 32 + lkg * 8;
            short8 raw = *(const short8*)p;
#pragma unroll
            for (int j = 0; j < 8; ++j) {
                int k = kt * 32 + lkg * 8 + j;
                float v = bf2f((ushort)raw[j]) * scs[k] + shs[k];
                v = v > 0.f ? v : SLOPE * v;
                ushort hb = f2bf(v);
                ah[kt][j] = (short)hb;
                al[kt][j] = (short)f2bf(v - bf2f(hb));
            }
        }
        f32x4 acc[4];
#pragma unroll
        for (int ct = 0; ct < 4; ++ct) {
            float bb = bias[ct];
            acc[ct][0] = bb; acc[ct][1] = bb; acc[ct][2] = bb; acc[ct][3] = bb;
        }
#pragma unroll
        for (int kt = 0; kt < 4; ++kt) {
#pragma unroll
            for (int ct = 0; ct < 4; ++ct) {
                short8 wh = *(const short8*)&wf[0][kt][ct][lane][0];
                short8 wl = *(const short8*)&wf[1][kt][ct][lane][0];
                acc[ct] = __builtin_amdgcn_mfma_f32_16x16x32_bf16(ah[kt], wh, acc[ct], 0, 0, 0);
                acc[ct] = __builtin_amdgcn_mfma_f32_16x16x32_bf16(al[kt], wh, acc[ct], 0, 0, 0);
                acc[ct] = __builtin_amdgcn_mfma_f32_16x16x32_bf16(ah[kt], wl, acc[ct], 0, 0, 0);
            }
        }
#pragma unroll
        for (int j = 0; j < 4; ++j) {
            float ss = acc[0][j] * acc[0][j];
#pragma unroll
            for (int ct = 1; ct < 4; ++ct) ss = fmaf(acc[ct][j], acc[ct][j], ss);
            ss += __shfl_xor(ss, 1, 64);
            ss += __shfl_xor(ss, 2, 64);
            ss += __shfl_xor(ss, 4, 64);
            ss += __shfl_xor(ss, 8, 64);
            float srow = NSCALE / fmaxf(sqrtf(ss), 1e-12f);
            int row = (int)r0 + lkg * 4 + j;
            if (row < n) {
                float dr = dinv[row];
#pragma unroll
                for (int ct = 0; ct < 4; ++ct) {
                    float lv = acc[ct][j];
                    l_ext[(size_t)row * 128 + ct * 16 + lrow] = f2bf(lv * dr);
                    l_ext[(size_t)row * 128 + 64 + ct * 16 + lrow] = f2bf(lv * srow * dr);
                }
            }
        }
    }
}

// pull SpMM2 over l_ext (256B rows: [l' | l'*s]), weightless, quarter-wave
__global__ __launch_bounds__(512) void k_spmm2_csr(const int* __restrict__ rowptr,
        const int* __restrict__ col, const uint4* __restrict__ le4,
        const float* __restrict__ dinv, const float* __restrict__ noise,
        float* __restrict__ mu, float* __restrict__ lsd, float* __restrict__ zeta,
        int n) {
    int node = blockIdx.x * 8 + ((int)threadIdx.x >> 6);
    if (node >= n) return;
    int lane = threadIdx.x & 63;
    int q = lane >> 4, g = lane & 15;
    int beg = rowptr[node], end = rowptr[node + 1];
    float a[8];
#pragma unroll
    for (int j = 0; j < 8; ++j) a[j] = 0.f;
    if (q == 0) add8(le4[(size_t)node * 16 + g], a);  // self-loop
    int p = beg;
    for (; p + 16 <= end; p += 16) {
        int c0 = col[p + q], c1 = col[p + 4 + q];
        int c2 = col[p + 8 + q], c3 = col[p + 12 + q];
        uint4 v0 = le4[(size_t)c0 * 16 + g];
        uint4 v1 = le4[(size_t)c1 * 16 + g];
        uint4 v2 = le4[(size_t)c2 * 16 + g];
        uint4 v3 = le4[(size_t)c3 * 16 + g];
        add8(v0, a); add8(v1, a); add8(v2, a); add8(v3, a);
    }
    if (p + 8 <= end) {
        int c0 = col[p + q], c1 = col[p + 4 + q];
        uint4 v0 = le4[(size_t)c0 * 16 + g];
        uint4 v1 = le4[(size_t)c1 * 16 + g];
        add8(v0, a); add8(v1, a);
        p += 8;
    }
    if (p < end) {
        int i0 = p + q, i1 = p + 4 + q;
        int c0 = col[i0 < end ? i0 : end - 1];
        int c1 = col[i1 < end ? i1 : end - 1];
        float w0 = (i0 < end) ? 1.f : 0.f;
        float w1 = (i1 < end) ? 1.f : 0.f;
        fma8(le4[(size_t)c0 * 16 + g], w0, a);
        fma8(le4[(size_t)c1 * 16 + g], w1, a);
    }
#pragma unroll
    for (int j = 0; j < 8; ++j) {
        a[j] += __shfl_xor(a[j], 16, 64);
        a[j] += __shfl_xor(a[j], 32, 64);
    }
    if (q == 0) {
        float di = dinv[node];
#pragma unroll
        for (int j = 0; j < 8; ++j) a[j] *= di;
        float b[8];
#pragma unroll
        for (int j = 0; j < 8; ++j) b[j] = __shfl_xor(a[j], 8, 64);
        if (g < 8) {
            size_t idx = (size_t)node * 64 + g * 8;
            f32x4 m0 = {a[0], a[1], a[2], a[3]};
            f32x4 m1 = {a[4], a[5], a[6], a[7]};
            *(f32x4*)(mu + idx) = m0;
            *(f32x4*)(mu + idx + 4) = m1;
            f32x4 n0 = *(const f32x4*)(noise + idx);
            f32x4 n1 = *(const f32x4*)(noise + idx + 4);
            f32x4 z0, z1;
            z0[0] = a[0] + n0[0] * expf(b[0]);
            z0[1] = a[1] + n0[1] * expf(b[1]);
            z0[2] = a[2] + n0[2] * expf(b[2]);
            z0[3] = a[3] + n0[3] * expf(b[3]);
            z1[0] = a[4] + n1[0] * expf(b[4]);
            z1[1] = a[5] + n1[1] * expf(b[5]);
            z1[2] = a[6] + n1[2] * expf(b[6]);
            z1[3] = a[7] + n1[3] * expf(b[7]);
            *(f32x4*)(zeta + idx) = z0;
            *(f32x4*)(zeta + idx + 4) = z1;
        } else {
            size_t idx = (size_t)node * 64 + (g - 8) * 8;
            f32x4 l0 = {a[0], a[1], a[2], a[3]};
            f32x4 l1 = {a[4], a[5], a[6], a[7]};
            *(f32x4*)(lsd + idx) = l0;
            *(f32x4*)(lsd + idx + 4) = l1;
        }
    }
}

extern "C" void kernel_launch(void* const* d_in, const int* in_sizes, int n_in,
                              void* d_out, int out_size, void* d_ws, size_t ws_size,
                              hipStream_t stream) {
    const float* x     = (const float*)d_in[0];
    const int*   esrc  = (const int*)d_in[1];
    const int*   edst  = (const int*)d_in[2];
    const float* W1    = (const float*)d_in[3];
    const float* b1    = (const float*)d_in[4];
    const float* gamma = (const float*)d_in[5];
    const float* beta  = (const float*)d_in[6];
    const float* Wmu   = (const float*)d_in[7];
    const float* bmu   = (const float*)d_in[8];
    const float* noise = (const float*)d_in[9];
    int N = in_sizes[0] / D_IN;
    int E = in_sizes[1];
    int B = (N + NB - 1) >> BSH;
    int nwt = (N + 15) / 16;
    int ntile = (E + T1 - 1) / T1;

    float* out  = (float*)d_out;
    float* mu   = out;
    float* lsd  = out + (size_t)N * D_OUT;
    float* zeta = out + 2 * (size_t)N * D_OUT;

    char* ws = (char*)d_ws;
    size_t off = 0;
    auto alloc = [&](size_t bytes) {
        void* p = ws + off;
        off += (bytes + 255) & ~(size_t)255;
        return p;
    };
    float* accum  = (float*)alloc(1024);
    int* bcnt     = (int*)alloc((size_t)B * 4);
    size_t zbytes = off;  // accum + bcnt zeroed
    int* bbase    = (int*)alloc(((size_t)B + 1) * 4);
    int* tailE    = (int*)alloc((size_t)B * 4);
    int* rowptr   = (int*)alloc(((size_t)N + 1) * 4);
    float* dinv   = (float*)alloc((size_t)N * 4);
    int2* ep      = (int2*)alloc((size_t)E * 8);
    int* col      = (int*)alloc((size_t)E * 4);
    ushort* h_bf  = (ushort*)alloc((size_t)N * D_HID * 2);
    uint4* agg_bf = (uint4*)alloc((size_t)N * D_HID * 2);
    ushort* l_ext = (ushort*)alloc((size_t)N * 128 * 2);

    hipMemsetAsync(d_ws, 0, zbytes, stream);

    k_bhist<<<ntile, 256, 0, stream>>>(edst, bcnt, E, B);
    k_bscan<<<1, 512, 0, stream>>>(bcnt, bbase, tailE, B);
    k_part<<<ntile, 256, 0, stream>>>(esrc, edst, tailE, ep, E, B);
    k_csr<<<B, 256, 0, stream>>>(ep, bbase, rowptr, dinv, col, N, B);
    k_gemm1_mfma<<<512, 256, 0, stream>>>(x, W1, b1, dinv, h_bf, N, nwt);
    k_spmm1_csr<<<1024, 512, 0, stream>>>(rowptr, col, (const uint4*)h_bf, dinv, agg_bf, accum, N);
    k_bnfinal<<<1, 128, 0, stream>>>(accum, gamma, beta, 1.0f / (float)N);
    k_gemm2_mfma<<<512, 256, 0, stream>>>((const ushort*)agg_bf, Wmu, bmu, accum, dinv, l_ext, N, nwt);
    k_spmm2_csr<<<(N + 7) / 8, 512, 0, stream>>>(rowptr, col, (const uint4*)l_ext, dinv, noise, mu, lsd, zeta, N);
}

// Round 9
// 317.547 us; speedup vs baseline: 1.4303x; 1.0090x over previous
//
#include <hip/hip_runtime.h>
#include <hip/hip_bf16.h>
#include <math.h>

#define D_IN 128
#define D_HID 128
#define D_OUT 64
#define BN_EPS 1e-5f
#define SLOPE 0.01f
#define NSCALE 1.8f

#define BSH 8          // nodes per bucket = 256
#define NB 256
#define T1 4096        // edges per partition tile
#define COLCAP 8192
#define LSTRIDE 192    // bytes per l_ext row: 64 bf16 l' + f32 s @128

typedef __attribute__((ext_vector_type(8))) short short8;
typedef __attribute__((ext_vector_type(4))) float f32x4;

__device__ inline void atomAddF(float* p, float v) {
#if defined(__gfx90a__) || defined(__gfx942__) || defined(__gfx950__)
    unsafeAtomicAdd(p, v);
#else
    atomicAdd(p, v);
#endif
}

__device__ inline ushort f2bf(float f) {  // RNE
    union { float f; uint u; } v; v.f = f;
    uint r = v.u + 0x7fff + ((v.u >> 16) & 1);
    return (ushort)(r >> 16);
}
__device__ inline float bf2f(ushort b) {
    union { uint u; float f; } v; v.u = ((uint)b) << 16;
    return v.f;
}
__device__ inline float bflo(uint u) { return __uint_as_float(u << 16); }
__device__ inline float bfhi(uint u) { return __uint_as_float(u & 0xffff0000u); }

__device__ inline void add8(uint4 v, float a[8]) {
    a[0] += bflo(v.x); a[1] += bfhi(v.x);
    a[2] += bflo(v.y); a[3] += bfhi(v.y);
    a[4] += bflo(v.z); a[5] += bfhi(v.z);
    a[6] += bflo(v.w); a[7] += bfhi(v.w);
}
__device__ inline void fma8(uint4 v, float w, float a[8]) {
    a[0] = fmaf(bflo(v.x), w, a[0]);
    a[1] = fmaf(bfhi(v.x), w, a[1]);
    a[2] = fmaf(bflo(v.y), w, a[2]);
    a[3] = fmaf(bfhi(v.y), w, a[3]);
    a[4] = fmaf(bflo(v.z), w, a[4]);
    a[5] = fmaf(bfhi(v.z), w, a[5]);
    a[6] = fmaf(bflo(v.w), w, a[6]);
    a[7] = fmaf(bfhi(v.w), w, a[7]);
}
// dual accumulate: am += v*w ; al += v*sv*w
__device__ inline void acc8(uint4 v, float sv, float w, float am[8], float al[8]) {
    float e;
    e = bflo(v.x) * w; am[0] += e; al[0] = fmaf(e, sv, al[0]);
    e = bfhi(v.x) * w; am[1] += e; al[1] = fmaf(e, sv, al[1]);
    e = bflo(v.y) * w; am[2] += e; al[2] = fmaf(e, sv, al[2]);
    e = bfhi(v.y) * w; am[3] += e; al[3] = fmaf(e, sv, al[3]);
    e = bflo(v.z) * w; am[4] += e; al[4] = fmaf(e, sv, al[4]);
    e = bfhi(v.z) * w; am[5] += e; al[5] = fmaf(e, sv, al[5]);
    e = bflo(v.w) * w; am[6] += e; al[6] = fmaf(e, sv, al[6]);
    e = bfhi(v.w) * w; am[7] += e; al[7] = fmaf(e, sv, al[7]);
}

// ---- bucket histogram (LDS-staged) -------------------------------------
__global__ __launch_bounds__(256) void k_bhist(const int* __restrict__ dst,
        int* __restrict__ bcnt, int E, int B) {
    __shared__ int h[512];
    for (int i = threadIdx.x; i < 512; i += 256) h[i] = 0;
    __syncthreads();
    int beg = blockIdx.x * T1;
    int end = min(beg + T1, E);
    for (int e = beg + threadIdx.x; e < end; e += 256)
        atomicAdd(&h[dst[e] >> BSH], 1);
    __syncthreads();
    for (int i = threadIdx.x; i < B; i += 256)
        if (h[i]) atomicAdd(&bcnt[i], h[i]);
}

// ---- bucket base scan (single block, B <= 512) -------------------------
__global__ __launch_bounds__(512) void k_bscan(const int* __restrict__ bcnt,
        int* __restrict__ bbase, int* __restrict__ tailE, int B) {
    __shared__ int sh[512];
    int t = threadIdx.x;
    int v = (t < B) ? bcnt[t] : 0;
    sh[t] = v;
    __syncthreads();
    for (int o = 1; o < 512; o <<= 1) {
        int u = (t >= o) ? sh[t - o] : 0;
        __syncthreads();
        sh[t] += u;
        __syncthreads();
    }
    int excl = sh[t] - v;
    if (t < B) { bbase[t] = excl; tailE[t] = excl; }
    if (t == B - 1) bbase[B] = excl + v;
}

// ---- partition edges into bucket regions (LDS reorder, coalesced out) --
__global__ __launch_bounds__(256) void k_part(const int* __restrict__ src,
        const int* __restrict__ dst, int* __restrict__ tailE,
        int2* __restrict__ ep, int E, int B) {
    __shared__ int h[512], off[512], gb[512], cur[512];
    __shared__ int ps[256];
    __shared__ int2 ro[T1];
    int tid = threadIdx.x;
    for (int i = tid; i < 512; i += 256) h[i] = 0;
    __syncthreads();
    int beg = blockIdx.x * T1;
    int cnt = min(T1, E - beg);
    int s[16], d[16];
#pragma unroll
    for (int k = 0; k < 16; ++k) {
        int e = beg + tid + k * 256;
        if (e < E) {
            s[k] = src[e]; d[k] = dst[e];
            atomicAdd(&h[d[k] >> BSH], 1);
        } else d[k] = -1;
    }
    __syncthreads();
    int pa = h[2 * tid], pb = h[2 * tid + 1];
    ps[tid] = pa + pb;
    __syncthreads();
    int vv = ps[tid];
    for (int o = 1; o < 256; o <<= 1) {
        int u = (tid >= o) ? ps[tid - o] : 0;
        __syncthreads();
        ps[tid] += u;
        __syncthreads();
    }
    int excl = ps[tid] - vv;
    off[2 * tid] = excl;       off[2 * tid + 1] = excl + pa;
    cur[2 * tid] = excl;       cur[2 * tid + 1] = excl + pa;
    if (2 * tid < B && pa > 0)      gb[2 * tid] = atomicAdd(&tailE[2 * tid], pa);
    if (2 * tid + 1 < B && pb > 0)  gb[2 * tid + 1] = atomicAdd(&tailE[2 * tid + 1], pb);
    __syncthreads();
#pragma unroll
    for (int k = 0; k < 16; ++k) {
        if (d[k] >= 0) {
            int b = d[k] >> BSH;
            int p = atomicAdd(&cur[b], 1);
            ro[p] = make_int2(s[k], d[k]);
        }
    }
    __syncthreads();
    for (int i = tid; i < cnt; i += 256) {
        int2 e = ro[i];
        int b = e.y >> BSH;
        ep[gb[b] + (i - off[b])] = e;
    }
}

// ---- per-bucket: deg/rowptr/dinv + CSR col build in LDS ----------------
__global__ __launch_bounds__(256) void k_csr(const int2* __restrict__ ep,
        const int* __restrict__ bbase, int* __restrict__ rowptr,
        float* __restrict__ dinv, int* __restrict__ col, int n, int B) {
    int b = blockIdx.x;
    int lo = b << BSH;
    int hi = min(lo + NB, n);
    int nn = hi - lo;
    int ebeg = bbase[b], eend = bbase[b + 1], cnt = eend - ebeg;
    __shared__ int h[NB], pfx[NB], cur[NB];
    __shared__ int colbuf[COLCAP];
    int tid = threadIdx.x;
    if (tid < NB) h[tid] = 0;
    __syncthreads();
    for (int i = tid; i < cnt; i += 256)
        atomicAdd(&h[ep[ebeg + i].y - lo], 1);
    __syncthreads();
    int v = (tid < nn) ? h[tid] : 0;
    pfx[tid] = v;
    __syncthreads();
    for (int o = 1; o < 256; o <<= 1) {
        int u = (tid >= o) ? pfx[tid - o] : 0;
        __syncthreads();
        pfx[tid] += u;
        __syncthreads();
    }
    int excl = pfx[tid] - v;
    if (tid < nn) {
        rowptr[lo + tid] = ebeg + excl;
        dinv[lo + tid] = rsqrtf((float)v + 1.0f);
        cur[tid] = excl;
    }
    if (b == B - 1 && tid == 0) rowptr[n] = eend;
    __syncthreads();
    if (cnt <= COLCAP) {
        for (int i = tid; i < cnt; i += 256) {
            int2 e = ep[ebeg + i];
            int p = atomicAdd(&cur[e.y - lo], 1);
            colbuf[p] = e.x;
        }
        __syncthreads();
        for (int i = tid; i < cnt; i += 256) col[ebeg + i] = colbuf[i];
    } else {
        for (int i = tid; i < cnt; i += 256) {
            int2 e = ep[ebeg + i];
            int p = atomicAdd(&cur[e.y - lo], 1);
            col[ebeg + p] = e.x;
        }
    }
}

// h_bf = bf16((x @ W1 + b1) * dinv[row]). Split-bf16 MFMA, W1 fragments in LDS.
__global__ __launch_bounds__(256) void k_gemm1_mfma(const float* __restrict__ x,
        const float* __restrict__ W1, const float* __restrict__ b1,
        const float* __restrict__ dinv, ushort* __restrict__ h_bf, int n, int nwt) {
    __shared__ ushort wf[2][4][8][64][8];  // 64KB
    int t = threadIdx.x;
    for (int i = t; i < 16384; i += 256) {
        int k = i >> 7, nn = i & 127;
        float v = W1[i];
        ushort hi = f2bf(v);
        ushort lo = f2bf(v - bf2f(hi));
        int kt = k >> 5, ct = nn >> 4;
        int lane = ((k >> 3) & 3) * 16 + (nn & 15);
        int j = k & 7;
        wf[0][kt][ct][lane][j] = hi;
        wf[1][kt][ct][lane][j] = lo;
    }
    __syncthreads();
    int wid = t >> 6, lane = t & 63;
    int lrow = lane & 15, lkg = lane >> 4;
    float bias[8];
#pragma unroll
    for (int ct = 0; ct < 8; ++ct) bias[ct] = b1[ct * 16 + lrow];
    int stride = gridDim.x * 4;
    for (int wt = blockIdx.x * 4 + wid; wt < nwt; wt += stride) {
        size_t r0 = (size_t)wt * 16;
        int rr = (int)r0 + lrow;
        if (rr >= n) rr = n - 1;
        short8 ah[4], al[4];
#pragma unroll
        for (int kt = 0; kt < 4; ++kt) {
            const float* p = x + (size_t)rr * 128 + kt * 32 + lkg * 8;
            float va[8];
            *(f32x4*)&va[0] = *(const f32x4*)p;
            *(f32x4*)&va[4] = *(const f32x4*)(p + 4);
#pragma unroll
            for (int j = 0; j < 8; ++j) {
                ushort hb = f2bf(va[j]);
                ah[kt][j] = (short)hb;
                al[kt][j] = (short)f2bf(va[j] - bf2f(hb));
            }
        }
        f32x4 acc[8];
#pragma unroll
        for (int ct = 0; ct < 8; ++ct) {
            float bb = bias[ct];
            acc[ct][0] = bb; acc[ct][1] = bb; acc[ct][2] = bb; acc[ct][3] = bb;
        }
#pragma unroll
        for (int kt = 0; kt < 4; ++kt) {
#pragma unroll
            for (int ct = 0; ct < 8; ++ct) {
                short8 wh = *(const short8*)&wf[0][kt][ct][lane][0];
                short8 wl = *(const short8*)&wf[1][kt][ct][lane][0];
                acc[ct] = __builtin_amdgcn_mfma_f32_16x16x32_bf16(ah[kt], wh, acc[ct], 0, 0, 0);
                acc[ct] = __builtin_amdgcn_mfma_f32_16x16x32_bf16(al[kt], wh, acc[ct], 0, 0, 0);
                acc[ct] = __builtin_amdgcn_mfma_f32_16x16x32_bf16(ah[kt], wl, acc[ct], 0, 0, 0);
            }
        }
#pragma unroll
        for (int j = 0; j < 4; ++j) {
            int row = (int)r0 + lkg * 4 + j;
            if (row < n) {
                float dr = dinv[row];
#pragma unroll
                for (int ct = 0; ct < 8; ++ct)
                    h_bf[(size_t)row * 128 + ct * 16 + lrow] = f2bf(acc[ct][j] * dr);
            }
        }
    }
}

// pull SpMM1, weightless: agg[d] = dinv[d]*(sum_in h'[src] + h'[d]).
__global__ __launch_bounds__(512) void k_spmm1_csr(const int* __restrict__ rowptr,
        const int* __restrict__ col, const uint4* __restrict__ hb4,
        const float* __restrict__ dinv, uint4* __restrict__ agg_bf,
        float* __restrict__ accum, int n) {
    __shared__ float red[8][16][8];
    int t = threadIdx.x;
    int wid = t >> 6, lane = t & 63;
    int q = lane >> 4, g = lane & 15;
    int gw = blockIdx.x * 8 + wid;
    int nw = gridDim.x * 8;
    float sx[8], sq[8];
#pragma unroll
    for (int j = 0; j < 8; ++j) { sx[j] = 0.f; sq[j] = 0.f; }
    for (int node = gw; node < n; node += nw) {
        int beg = rowptr[node], end = rowptr[node + 1];
        float a[8];
#pragma unroll
        for (int j = 0; j < 8; ++j) a[j] = 0.f;
        if (q == 0) add8(hb4[(size_t)node * 16 + g], a);  // self-loop
        int p = beg;
        for (; p + 16 <= end; p += 16) {
            int c0 = col[p + q], c1 = col[p + 4 + q];
            int c2 = col[p + 8 + q], c3 = col[p + 12 + q];
            uint4 v0 = hb4[(size_t)c0 * 16 + g];
            uint4 v1 = hb4[(size_t)c1 * 16 + g];
            uint4 v2 = hb4[(size_t)c2 * 16 + g];
            uint4 v3 = hb4[(size_t)c3 * 16 + g];
            add8(v0, a); add8(v1, a); add8(v2, a); add8(v3, a);
        }
        if (p + 8 <= end) {
            int c0 = col[p + q], c1 = col[p + 4 + q];
            uint4 v0 = hb4[(size_t)c0 * 16 + g];
            uint4 v1 = hb4[(size_t)c1 * 16 + g];
            add8(v0, a); add8(v1, a);
            p += 8;
        }
        if (p < end) {
            int i0 = p + q, i1 = p + 4 + q;
            int c0 = col[i0 < end ? i0 : end - 1];
            int c1 = col[i1 < end ? i1 : end - 1];
            float w0 = (i0 < end) ? 1.f : 0.f;
            float w1 = (i1 < end) ? 1.f : 0.f;
            fma8(hb4[(size_t)c0 * 16 + g], w0, a);
            fma8(hb4[(size_t)c1 * 16 + g], w1, a);
        }
#pragma unroll
        for (int j = 0; j < 8; ++j) {
            a[j] += __shfl_xor(a[j], 16, 64);
            a[j] += __shfl_xor(a[j], 32, 64);
        }
        if (q == 0) {
            float di = dinv[node];
#pragma unroll
            for (int j = 0; j < 8; ++j) a[j] *= di;
            uint4 pk;
            pk.x = ((uint)f2bf(a[1]) << 16) | (uint)f2bf(a[0]);
            pk.y = ((uint)f2bf(a[3]) << 16) | (uint)f2bf(a[2]);
            pk.z = ((uint)f2bf(a[5]) << 16) | (uint)f2bf(a[4]);
            pk.w = ((uint)f2bf(a[7]) << 16) | (uint)f2bf(a[6]);
            agg_bf[(size_t)node * 16 + g] = pk;
#pragma unroll
            for (int j = 0; j < 8; ++j) {
                sx[j] += a[j];
                sq[j] = fmaf(a[j], a[j], sq[j]);
            }
        }
    }
    if (q == 0) {
#pragma unroll
        for (int j = 0; j < 8; ++j) red[wid][g][j] = sx[j];
    }
    __syncthreads();
    if (t < 128) {
        float v = 0.f;
        for (int w = 0; w < 8; ++w) v += red[w][t >> 3][t & 7];
        atomAddF(&accum[t], v);
    }
    __syncthreads();
    if (q == 0) {
#pragma unroll
        for (int j = 0; j < 8; ++j) red[wid][g][j] = sq[j];
    }
    __syncthreads();
    if (t < 128) {
        float v = 0.f;
        for (int w = 0; w < 8; ++w) v += red[w][t >> 3][t & 7];
        atomAddF(&accum[128 + t], v);
    }
}

// l_ext rows (192B): [ 64x bf16 l*dinv | f32 s @128 ]; BN finalize fused in stage.
__global__ __launch_bounds__(256) void k_gemm2_mfma(const ushort* __restrict__ agg_bf,
        const float* __restrict__ Wmu, const float* __restrict__ bmu,
        const float* __restrict__ accum, const float* __restrict__ gamma,
        const float* __restrict__ beta, const float* __restrict__ dinv,
        char* __restrict__ l_ext, float inv_n, int n, int nwt) {
    __shared__ ushort wf[2][4][4][64][8];  // 32KB
    __shared__ float scs[D_HID], shs[D_HID];
    int t = threadIdx.x;
    for (int i = t; i < 8192; i += 256) {
        int k = i >> 6, nn = i & 63;
        float v = Wmu[i];
        ushort hi = f2bf(v);
        ushort lo = f2bf(v - bf2f(hi));
        int kt = k >> 5, ct = nn >> 4;
        int lane = ((k >> 3) & 3) * 16 + (nn & 15);
        int j = k & 7;
        wf[0][kt][ct][lane][j] = hi;
        wf[1][kt][ct][lane][j] = lo;
    }
    for (int i = t; i < D_HID; i += 256) {  // fused bnfinal
        float mean = accum[i] * inv_n;
        float var = accum[D_HID + i] * inv_n - mean * mean;
        float sc = gamma[i] * rsqrtf(var + BN_EPS);
        scs[i] = sc;
        shs[i] = beta[i] - mean * sc;
    }
    __syncthreads();
    int wid = t >> 6, lane = t & 63;
    int lrow = lane & 15, lkg = lane >> 4;
    float bias[4];
#pragma unroll
    for (int ct = 0; ct < 4; ++ct) bias[ct] = bmu[ct * 16 + lrow];
    int stride = gridDim.x * 4;
    for (int wt = blockIdx.x * 4 + wid; wt < nwt; wt += stride) {
        size_t r0 = (size_t)wt * 16;
        int rr = (int)r0 + lrow;
        if (rr >= n) rr = n - 1;
        short8 ah[4], al[4];
#pragma unroll
        for (int kt = 0; kt < 4; ++kt) {
            const ushort* p = agg_bf + (size_t)rr * 128 + kt * 32 + lkg * 8;
            short8 raw = *(const short8*)p;
#pragma unroll
            for (int j = 0; j < 8; ++j) {
                int k = kt * 32 + lkg * 8 + j;
                float v = bf2f((ushort)raw[j]) * scs[k] + shs[k];
                v = v > 0.f ? v : SLOPE * v;
                ushort hb = f2bf(v);
                ah[kt][j] = (short)hb;
                al[kt][j] = (short)f2bf(v - bf2f(hb));
            }
        }
        f32x4 acc[4];
#pragma unroll
        for (int ct = 0; ct < 4; ++ct) {
            float bb = bias[ct];
            acc[ct][0] = bb; acc[ct][1] = bb; acc[ct][2] = bb; acc[ct][3] = bb;
        }
#pragma unroll
        for (int kt = 0; kt < 4; ++kt) {
#pragma unroll
            for (int ct = 0; ct < 4; ++ct) {
                short8 wh = *(const short8*)&wf[0][kt][ct][lane][0];
                short8 wl = *(const short8*)&wf[1][kt][ct][lane][0];
                acc[ct] = __builtin_amdgcn_mfma_f32_16x16x32_bf16(ah[kt], wh, acc[ct], 0, 0, 0);
                acc[ct] = __builtin_amdgcn_mfma_f32_16x16x32_bf16(al[kt], wh, acc[ct], 0, 0, 0);
                acc[ct] = __builtin_amdgcn_mfma_f32_16x16x32_bf16(ah[kt], wl, acc[ct], 0, 0, 0);
            }
        }
#pragma unroll
        for (int j = 0; j < 4; ++j) {
            float ss = acc[0][j] * acc[0][j];
#pragma unroll
            for (int ct = 1; ct < 4; ++ct) ss = fmaf(acc[ct][j], acc[ct][j], ss);
            ss += __shfl_xor(ss, 1, 64);
            ss += __shfl_xor(ss, 2, 64);
            ss += __shfl_xor(ss, 4, 64);
            ss += __shfl_xor(ss, 8, 64);
            float srow = NSCALE / fmaxf(sqrtf(ss), 1e-12f);
            int row = (int)r0 + lkg * 4 + j;
            if (row < n) {
                float dr = dinv[row];
                char* base = l_ext + (size_t)row * LSTRIDE;
#pragma unroll
                for (int ct = 0; ct < 4; ++ct)
                    *(ushort*)(base + (ct * 16 + lrow) * 2) = f2bf(acc[ct][j] * dr);
                if (lrow == 0) *(float*)(base + 128) = srow;
            }
        }
    }
}

// pull SpMM2 over l_ext (192B rows), octet-per-edge (8 edges/wave in flight),
// lane-local dual accumulation (mu & logstd), fused reparam.
__global__ __launch_bounds__(512) void k_spmm2_csr(const int* __restrict__ rowptr,
        const int* __restrict__ col, const char* __restrict__ lb,
        const float* __restrict__ dinv, const float* __restrict__ noise,
        float* __restrict__ mu, float* __restrict__ lsd, float* __restrict__ zeta,
        int n) {
    int node = blockIdx.x * 8 + ((int)threadIdx.x >> 6);
    if (node >= n) return;
    int lane = threadIdx.x & 63;
    int oct = lane >> 3, g = lane & 7;  // lane holds cols 8g..8g+7
    int beg = rowptr[node], end = rowptr[node + 1];
    float am[8], al[8];
#pragma unroll
    for (int j = 0; j < 8; ++j) { am[j] = 0.f; al[j] = 0.f; }
    if (oct == 0) {  // self-loop
        const char* rb = lb + (size_t)node * LSTRIDE;
        uint4 v = *(const uint4*)(rb + g * 16);
        float sv = *(const float*)(rb + 128);
        acc8(v, sv, 1.f, am, al);
    }
    int p = beg;
    for (; p + 16 <= end; p += 16) {
        int c0 = col[p + oct], c1 = col[p + 8 + oct];
        const char* r0 = lb + (size_t)c0 * LSTRIDE;
        const char* r1 = lb + (size_t)c1 * LSTRIDE;
        uint4 v0 = *(const uint4*)(r0 + g * 16);
        float s0 = *(const float*)(r0 + 128);
        uint4 v1 = *(const uint4*)(r1 + g * 16);
        float s1 = *(const float*)(r1 + 128);
        acc8(v0, s0, 1.f, am, al);
        acc8(v1, s1, 1.f, am, al);
    }
    if (p + 8 <= end) {
        int c0 = col[p + oct];
        const char* r0 = lb + (size_t)c0 * LSTRIDE;
        uint4 v0 = *(const uint4*)(r0 + g * 16);
        float s0 = *(const float*)(r0 + 128);
        acc8(v0, s0, 1.f, am, al);
        p += 8;
    }
    if (p < end) {
        int i0 = p + oct;
        int c0 = col[i0 < end ? i0 : end - 1];
        float w0 = (i0 < end) ? 1.f : 0.f;
        const char* r0 = lb + (size_t)c0 * LSTRIDE;
        uint4 v0 = *(const uint4*)(r0 + g * 16);
        float s0 = *(const float*)(r0 + 128);
        acc8(v0, s0, w0, am, al);
    }
#pragma unroll
    for (int j = 0; j < 8; ++j) {
        am[j] += __shfl_xor(am[j], 8, 64);
        am[j] += __shfl_xor(am[j], 16, 64);
        am[j] += __shfl_xor(am[j], 32, 64);
        al[j] += __shfl_xor(al[j], 8, 64);
        al[j] += __shfl_xor(al[j], 16, 64);
        al[j] += __shfl_xor(al[j], 32, 64);
    }
    if (lane < 8) {
        float di = dinv[node];
        size_t idx = (size_t)node * 64 + lane * 8;
        f32x4 m0, m1, l0, l1, z0, z1;
#pragma unroll
        for (int j = 0; j < 4; ++j) {
            m0[j] = am[j] * di;     m1[j] = am[j + 4] * di;
            l0[j] = al[j] * di;     l1[j] = al[j + 4] * di;
        }
        f32x4 n0 = *(const f32x4*)(noise + idx);
        f32x4 n1 = *(const f32x4*)(noise + idx + 4);
#pragma unroll
        for (int j = 0; j < 4; ++j) {
            z0[j] = m0[j] + n0[j] * expf(l0[j]);
            z1[j] = m1[j] + n1[j] * expf(l1[j]);
        }
        *(f32x4*)(mu + idx) = m0;   *(f32x4*)(mu + idx + 4) = m1;
        *(f32x4*)(lsd + idx) = l0;  *(f32x4*)(lsd + idx + 4) = l1;
        *(f32x4*)(zeta + idx) = z0; *(f32x4*)(zeta + idx + 4) = z1;
    }
}

extern "C" void kernel_launch(void* const* d_in, const int* in_sizes, int n_in,
                              void* d_out, int out_size, void* d_ws, size_t ws_size,
                              hipStream_t stream) {
    const float* x     = (const float*)d_in[0];
    const int*   esrc  = (const int*)d_in[1];
    const int*   edst  = (const int*)d_in[2];
    const float* W1    = (const float*)d_in[3];
    const float* b1    = (const float*)d_in[4];
    const float* gamma = (const float*)d_in[5];
    const float* beta  = (const float*)d_in[6];
    const float* Wmu   = (const float*)d_in[7];
    const float* bmu   = (const float*)d_in[8];
    const float* noise = (const float*)d_in[9];
    int N = in_sizes[0] / D_IN;
    int E = in_sizes[1];
    int B = (N + NB - 1) >> BSH;
    int nwt = (N + 15) / 16;
    int ntile = (E + T1 - 1) / T1;

    float* out  = (float*)d_out;
    float* mu   = out;
    float* lsd  = out + (size_t)N * D_OUT;
    float* zeta = out + 2 * (size_t)N * D_OUT;

    char* ws = (char*)d_ws;
    size_t off = 0;
    auto alloc = [&](size_t bytes) {
        void* p = ws + off;
        off += (bytes + 255) & ~(size_t)255;
        return p;
    };
    float* accum  = (float*)alloc(1024);
    int* bcnt     = (int*)alloc((size_t)B * 4);
    size_t zbytes = off;  // accum + bcnt zeroed
    int* bbase    = (int*)alloc(((size_t)B + 1) * 4);
    int* tailE    = (int*)alloc((size_t)B * 4);
    int* rowptr   = (int*)alloc(((size_t)N + 1) * 4);
    float* dinv   = (float*)alloc((size_t)N * 4);
    int2* ep      = (int2*)alloc((size_t)E * 8);
    int* col      = (int*)alloc((size_t)E * 4);
    ushort* h_bf  = (ushort*)alloc((size_t)N * D_HID * 2);
    uint4* agg_bf = (uint4*)alloc((size_t)N * D_HID * 2);
    char* l_ext   = (char*)alloc((size_t)N * LSTRIDE);

    hipMemsetAsync(d_ws, 0, zbytes, stream);

    k_bhist<<<ntile, 256, 0, stream>>>(edst, bcnt, E, B);
    k_bscan<<<1, 512, 0, stream>>>(bcnt, bbase, tailE, B);
    k_part<<<ntile, 256, 0, stream>>>(esrc, edst, tailE, ep, E, B);
    k_csr<<<B, 256, 0, stream>>>(ep, bbase, rowptr, dinv, col, N, B);
    k_gemm1_mfma<<<512, 256, 0, stream>>>(x, W1, b1, dinv, h_bf, N, nwt);
    k_spmm1_csr<<<2048, 512, 0, stream>>>(rowptr, col, (const uint4*)h_bf, dinv, agg_bf, accum, N);
    k_gemm2_mfma<<<512, 256, 0, stream>>>((const ushort*)agg_bf, Wmu, bmu, accum,
                                          gamma, beta, dinv, l_ext, 1.0f / (float)N, N, nwt);
    k_spmm2_csr<<<(N + 7) / 8, 512, 0, stream>>>(rowptr, col, l_ext, dinv, noise, mu, lsd, zeta, N);
}

// Round 10
// 311.577 us; speedup vs baseline: 1.4577x; 1.0192x over previous
//
#include <hip/hip_runtime.h>
#include <hip/hip_bf16.h>
#include <math.h>

#define D_IN 128
#define D_HID 128
#define D_OUT 64
#define BN_EPS 1e-5f
#define SLOPE 0.01f
#define NSCALE 1.8f

#define BSH 8          // nodes per bucket = 256
#define NB 256
#define T1 4096        // edges per partition tile
#define COLCAP 8192
#define LSTRIDE 192    // bytes per l_ext row: 64 bf16 l' + f32 s @128

typedef __attribute__((ext_vector_type(8))) short short8;
typedef __attribute__((ext_vector_type(4))) float f32x4;

__device__ inline void atomAddF(float* p, float v) {
#if defined(__gfx90a__) || defined(__gfx942__) || defined(__gfx950__)
    unsafeAtomicAdd(p, v);
#else
    atomicAdd(p, v);
#endif
}

__device__ inline ushort f2bf(float f) {  // RNE
    union { float f; uint u; } v; v.f = f;
    uint r = v.u + 0x7fff + ((v.u >> 16) & 1);
    return (ushort)(r >> 16);
}
__device__ inline float bf2f(ushort b) {
    union { uint u; float f; } v; v.u = ((uint)b) << 16;
    return v.f;
}
__device__ inline float bflo(uint u) { return __uint_as_float(u << 16); }
__device__ inline float bfhi(uint u) { return __uint_as_float(u & 0xffff0000u); }

__device__ inline void add4(uint2 v, float a[4]) {
    a[0] += bflo(v.x); a[1] += bfhi(v.x);
    a[2] += bflo(v.y); a[3] += bfhi(v.y);
}
__device__ inline void fma4(uint2 v, float w, float a[4]) {
    a[0] = fmaf(bflo(v.x), w, a[0]);
    a[1] = fmaf(bfhi(v.x), w, a[1]);
    a[2] = fmaf(bflo(v.y), w, a[2]);
    a[3] = fmaf(bfhi(v.y), w, a[3]);
}
// dual accumulate: am += v*w ; al += v*sv*w
__device__ inline void acc8(uint4 v, float sv, float w, float am[8], float al[8]) {
    float e;
    e = bflo(v.x) * w; am[0] += e; al[0] = fmaf(e, sv, al[0]);
    e = bfhi(v.x) * w; am[1] += e; al[1] = fmaf(e, sv, al[1]);
    e = bflo(v.y) * w; am[2] += e; al[2] = fmaf(e, sv, al[2]);
    e = bfhi(v.y) * w; am[3] += e; al[3] = fmaf(e, sv, al[3]);
    e = bflo(v.z) * w; am[4] += e; al[4] = fmaf(e, sv, al[4]);
    e = bfhi(v.z) * w; am[5] += e; al[5] = fmaf(e, sv, al[5]);
    e = bflo(v.w) * w; am[6] += e; al[6] = fmaf(e, sv, al[6]);
    e = bfhi(v.w) * w; am[7] += e; al[7] = fmaf(e, sv, al[7]);
}

// ---- bucket histogram (LDS-staged) -------------------------------------
__global__ __launch_bounds__(256) void k_bhist(const int* __restrict__ dst,
        int* __restrict__ bcnt, int E, int B) {
    __shared__ int h[512];
    for (int i = threadIdx.x; i < 512; i += 256) h[i] = 0;
    __syncthreads();
    int beg = blockIdx.x * T1;
    int end = min(beg + T1, E);
    for (int e = beg + threadIdx.x; e < end; e += 256)
        atomicAdd(&h[dst[e] >> BSH], 1);
    __syncthreads();
    for (int i = threadIdx.x; i < B; i += 256)
        if (h[i]) atomicAdd(&bcnt[i], h[i]);
}

// ---- bucket base scan (single block, B <= 512) -------------------------
__global__ __launch_bounds__(512) void k_bscan(const int* __restrict__ bcnt,
        int* __restrict__ bbase, int* __restrict__ tailE, int B) {
    __shared__ int sh[512];
    int t = threadIdx.x;
    int v = (t < B) ? bcnt[t] : 0;
    sh[t] = v;
    __syncthreads();
    for (int o = 1; o < 512; o <<= 1) {
        int u = (t >= o) ? sh[t - o] : 0;
        __syncthreads();
        sh[t] += u;
        __syncthreads();
    }
    int excl = sh[t] - v;
    if (t < B) { bbase[t] = excl; tailE[t] = excl; }
    if (t == B - 1) bbase[B] = excl + v;
}

// ---- partition edges into bucket regions; ep packed: src | dlocal<<24 --
__global__ __launch_bounds__(256) void k_part(const int* __restrict__ src,
        const int* __restrict__ dst, int* __restrict__ tailE,
        uint* __restrict__ ep, int E, int B) {
    __shared__ int h[512], off[512], gb[512], cur[512];
    __shared__ int ps[256];
    __shared__ int2 ro[T1];
    int tid = threadIdx.x;
    for (int i = tid; i < 512; i += 256) h[i] = 0;
    __syncthreads();
    int beg = blockIdx.x * T1;
    int cnt = min(T1, E - beg);
    int s[16], d[16];
#pragma unroll
    for (int k = 0; k < 16; ++k) {
        int e = beg + tid + k * 256;
        if (e < E) {
            s[k] = src[e]; d[k] = dst[e];
            atomicAdd(&h[d[k] >> BSH], 1);
        } else d[k] = -1;
    }
    __syncthreads();
    int pa = h[2 * tid], pb = h[2 * tid + 1];
    ps[tid] = pa + pb;
    __syncthreads();
    int vv = ps[tid];
    for (int o = 1; o < 256; o <<= 1) {
        int u = (tid >= o) ? ps[tid - o] : 0;
        __syncthreads();
        ps[tid] += u;
        __syncthreads();
    }
    int excl = ps[tid] - vv;
    off[2 * tid] = excl;       off[2 * tid + 1] = excl + pa;
    cur[2 * tid] = excl;       cur[2 * tid + 1] = excl + pa;
    if (2 * tid < B && pa > 0)      gb[2 * tid] = atomicAdd(&tailE[2 * tid], pa);
    if (2 * tid + 1 < B && pb > 0)  gb[2 * tid + 1] = atomicAdd(&tailE[2 * tid + 1], pb);
    __syncthreads();
#pragma unroll
    for (int k = 0; k < 16; ++k) {
        if (d[k] >= 0) {
            int b = d[k] >> BSH;
            int p = atomicAdd(&cur[b], 1);
            ro[p] = make_int2(s[k], d[k]);
        }
    }
    __syncthreads();
    for (int i = tid; i < cnt; i += 256) {
        int2 e = ro[i];
        int b = e.y >> BSH;
        ep[gb[b] + (i - off[b])] = (uint)e.x | ((uint)(e.y & (NB - 1)) << 24);
    }
}

// ---- per-bucket: deg/rowptr/dinv + CSR col build in LDS ----------------
__global__ __launch_bounds__(256) void k_csr(const uint* __restrict__ ep,
        const int* __restrict__ bbase, int* __restrict__ rowptr,
        float* __restrict__ dinv, int* __restrict__ col, int n, int B) {
    int b = blockIdx.x;
    int lo = b << BSH;
    int hi = min(lo + NB, n);
    int nn = hi - lo;
    int ebeg = bbase[b], eend = bbase[b + 1], cnt = eend - ebeg;
    __shared__ int h[NB], pfx[NB], cur[NB];
    __shared__ int colbuf[COLCAP];
    int tid = threadIdx.x;
    if (tid < NB) h[tid] = 0;
    __syncthreads();
    for (int i = tid; i < cnt; i += 256)
        atomicAdd(&h[ep[ebeg + i] >> 24], 1);
    __syncthreads();
    int v = (tid < nn) ? h[tid] : 0;
    pfx[tid] = v;
    __syncthreads();
    for (int o = 1; o < 256; o <<= 1) {
        int u = (tid >= o) ? pfx[tid - o] : 0;
        __syncthreads();
        pfx[tid] += u;
        __syncthreads();
    }
    int excl = pfx[tid] - v;
    if (tid < nn) {
        rowptr[lo + tid] = ebeg + excl;
        dinv[lo + tid] = rsqrtf((float)v + 1.0f);
        cur[tid] = excl;
    }
    if (b == B - 1 && tid == 0) rowptr[n] = eend;
    __syncthreads();
    if (cnt <= COLCAP) {
        for (int i = tid; i < cnt; i += 256) {
            uint e = ep[ebeg + i];
            int p = atomicAdd(&cur[e >> 24], 1);
            colbuf[p] = (int)(e & 0xFFFFFFu);
        }
        __syncthreads();
        for (int i = tid; i < cnt; i += 256) col[ebeg + i] = colbuf[i];
    } else {
        for (int i = tid; i < cnt; i += 256) {
            uint e = ep[ebeg + i];
            int p = atomicAdd(&cur[e >> 24], 1);
            col[ebeg + p] = (int)(e & 0xFFFFFFu);
        }
    }
}

// h' = bf16((x @ W1 + b1) * dinv[row]), stored as two half-tables
// (cols 0-63 at h_bf, cols 64-127 at h_bf + n*64). A split-bf16, W plain bf16.
__global__ __launch_bounds__(256) void k_gemm1_mfma(const float* __restrict__ x,
        const float* __restrict__ W1, const float* __restrict__ b1,
        const float* __restrict__ dinv, ushort* __restrict__ h_bf, int n, int nwt) {
    __shared__ ushort wf[4][8][64][8];  // [kt][ct][lane][j] = 32KB
    int t = threadIdx.x;
    for (int i = t; i < 16384; i += 256) {
        int k = i >> 7, nn = i & 127;
        int kt = k >> 5, ct = nn >> 4;
        int lane = ((k >> 3) & 3) * 16 + (nn & 15);
        int j = k & 7;
        wf[kt][ct][lane][j] = f2bf(W1[i]);
    }
    __syncthreads();
    size_t n64 = (size_t)n * 64;
    int wid = t >> 6, lane = t & 63;
    int lrow = lane & 15, lkg = lane >> 4;
    float bias[8];
#pragma unroll
    for (int ct = 0; ct < 8; ++ct) bias[ct] = b1[ct * 16 + lrow];
    int stride = gridDim.x * 4;
    for (int wt = blockIdx.x * 4 + wid; wt < nwt; wt += stride) {
        size_t r0 = (size_t)wt * 16;
        int rr = (int)r0 + lrow;
        if (rr >= n) rr = n - 1;
        short8 ah[4], al[4];
#pragma unroll
        for (int kt = 0; kt < 4; ++kt) {
            const float* p = x + (size_t)rr * 128 + kt * 32 + lkg * 8;
            float va[8];
            *(f32x4*)&va[0] = *(const f32x4*)p;
            *(f32x4*)&va[4] = *(const f32x4*)(p + 4);
#pragma unroll
            for (int j = 0; j < 8; ++j) {
                ushort hb = f2bf(va[j]);
                ah[kt][j] = (short)hb;
                al[kt][j] = (short)f2bf(va[j] - bf2f(hb));
            }
        }
        f32x4 acc[8];
#pragma unroll
        for (int ct = 0; ct < 8; ++ct) {
            float bb = bias[ct];
            acc[ct][0] = bb; acc[ct][1] = bb; acc[ct][2] = bb; acc[ct][3] = bb;
        }
#pragma unroll
        for (int kt = 0; kt < 4; ++kt) {
#pragma unroll
            for (int ct = 0; ct < 8; ++ct) {
                short8 wh = *(const short8*)&wf[kt][ct][lane][0];
                acc[ct] = __builtin_amdgcn_mfma_f32_16x16x32_bf16(ah[kt], wh, acc[ct], 0, 0, 0);
                acc[ct] = __builtin_amdgcn_mfma_f32_16x16x32_bf16(al[kt], wh, acc[ct], 0, 0, 0);
            }
        }
#pragma unroll
        for (int j = 0; j < 4; ++j) {
            int row = (int)r0 + lkg * 4 + j;
            if (row < n) {
                float dr = dinv[row];
#pragma unroll
                for (int ct = 0; ct < 8; ++ct)
                    h_bf[(size_t)(ct >> 2) * n64 + (size_t)row * 64 + (ct & 3) * 16 + lrow]
                        = f2bf(acc[ct][j] * dr);
            }
        }
    }
}

// pull SpMM1, feature-split pass: gathers 128B rows from a 12.8MB half-table.
// quarter-wave: 16 lanes x uint2 = 128B row, 4 edges/instr, 16 edges in flight.
// agg[d] = dinv[d]*(sum_in h'[src] + h'[d]); fused BN partial stats.
__global__ __launch_bounds__(512) void k_spmm1_csr(const int* __restrict__ rowptr,
        const int* __restrict__ col, const uint2* __restrict__ tbl,
        const float* __restrict__ dinv, uint2* __restrict__ aggq,
        float* __restrict__ accum, int n, int half) {
    __shared__ float red[8][16][4];
    int t = threadIdx.x;
    int wid = t >> 6, lane = t & 63;
    int q = lane >> 4, g = lane & 15;
    int gw = blockIdx.x * 8 + wid;
    int nw = gridDim.x * 8;
    float sx[4] = {0.f, 0.f, 0.f, 0.f}, sq[4] = {0.f, 0.f, 0.f, 0.f};
    for (int node = gw; node < n; node += nw) {
        int beg = rowptr[node], end = rowptr[node + 1];
        float a[4] = {0.f, 0.f, 0.f, 0.f};
        if (q == 0) add4(tbl[(size_t)node * 16 + g], a);  // self-loop
        int p = beg;
        for (; p + 16 <= end; p += 16) {
            int c0 = col[p + q], c1 = col[p + 4 + q];
            int c2 = col[p + 8 + q], c3 = col[p + 12 + q];
            uint2 v0 = tbl[(size_t)c0 * 16 + g];
            uint2 v1 = tbl[(size_t)c1 * 16 + g];
            uint2 v2 = tbl[(size_t)c2 * 16 + g];
            uint2 v3 = tbl[(size_t)c3 * 16 + g];
            add4(v0, a); add4(v1, a); add4(v2, a); add4(v3, a);
        }
        if (p + 8 <= end) {
            int c0 = col[p + q], c1 = col[p + 4 + q];
            uint2 v0 = tbl[(size_t)c0 * 16 + g];
            uint2 v1 = tbl[(size_t)c1 * 16 + g];
            add4(v0, a); add4(v1, a);
            p += 8;
        }
        if (p < end) {
            int i0 = p + q, i1 = p + 4 + q;
            int c0 = col[i0 < end ? i0 : end - 1];
            int c1 = col[i1 < end ? i1 : end - 1];
            float w0 = (i0 < end) ? 1.f : 0.f;
            float w1 = (i1 < end) ? 1.f : 0.f;
            fma4(tbl[(size_t)c0 * 16 + g], w0, a);
            fma4(tbl[(size_t)c1 * 16 + g], w1, a);
        }
#pragma unroll
        for (int j = 0; j < 4; ++j) {
            a[j] += __shfl_xor(a[j], 16, 64);
            a[j] += __shfl_xor(a[j], 32, 64);
        }
        if (q == 0) {
            float di = dinv[node];
#pragma unroll
            for (int j = 0; j < 4; ++j) a[j] *= di;
            uint2 pk;
            pk.x = ((uint)f2bf(a[1]) << 16) | (uint)f2bf(a[0]);
            pk.y = ((uint)f2bf(a[3]) << 16) | (uint)f2bf(a[2]);
            aggq[(size_t)node * 32 + half * 16 + g] = pk;
#pragma unroll
            for (int j = 0; j < 4; ++j) {
                sx[j] += a[j];
                sq[j] = fmaf(a[j], a[j], sq[j]);
            }
        }
    }
    // block stats: local col = 4g + j, global col = half*64 + 4g + j
    if (q == 0) {
#pragma unroll
        for (int j = 0; j < 4; ++j) red[wid][g][j] = sx[j];
    }
    __syncthreads();
    if (t < 64) {
        float v = 0.f;
        for (int w = 0; w < 8; ++w) v += red[w][t >> 2][t & 3];
        atomAddF(&accum[half * 64 + t], v);
    }
    __syncthreads();
    if (q == 0) {
#pragma unroll
        for (int j = 0; j < 4; ++j) red[wid][g][j] = sq[j];
    }
    __syncthreads();
    if (t < 64) {
        float v = 0.f;
        for (int w = 0; w < 8; ++w) v += red[w][t >> 2][t & 3];
        atomAddF(&accum[128 + half * 64 + t], v);
    }
}

// l_ext rows (192B): [ 64x bf16 l*dinv | f32 s @128 ]; BN finalize fused.
// A split-bf16, W plain bf16.
__global__ __launch_bounds__(256) void k_gemm2_mfma(const ushort* __restrict__ agg_bf,
        const float* __restrict__ Wmu, const float* __restrict__ bmu,
        const float* __restrict__ accum, const float* __restrict__ gamma,
        const float* __restrict__ beta, const float* __restrict__ dinv,
        char* __restrict__ l_ext, float inv_n, int n, int nwt) {
    __shared__ ushort wf[4][4][64][8];  // 16KB
    __shared__ float scs[D_HID], shs[D_HID];
    int t = threadIdx.x;
    for (int i = t; i < 8192; i += 256) {
        int k = i >> 6, nn = i & 63;
        int kt = k >> 5, ct = nn >> 4;
        int lane = ((k >> 3) & 3) * 16 + (nn & 15);
        int j = k & 7;
        wf[kt][ct][lane][j] = f2bf(Wmu[i]);
    }
    for (int i = t; i < D_HID; i += 256) {  // fused bnfinal
        float mean = accum[i] * inv_n;
        float var = accum[D_HID + i] * inv_n - mean * mean;
        float sc = gamma[i] * rsqrtf(var + BN_EPS);
        scs[i] = sc;
        shs[i] = beta[i] - mean * sc;
    }
    __syncthreads();
    int wid = t >> 6, lane = t & 63;
    int lrow = lane & 15, lkg = lane >> 4;
    float bias[4];
#pragma unroll
    for (int ct = 0; ct < 4; ++ct) bias[ct] = bmu[ct * 16 + lrow];
    int stride = gridDim.x * 4;
    for (int wt = blockIdx.x * 4 + wid; wt < nwt; wt += stride) {
        size_t r0 = (size_t)wt * 16;
        int rr = (int)r0 + lrow;
        if (rr >= n) rr = n - 1;
        short8 ah[4], al[4];
#pragma unroll
        for (int kt = 0; kt < 4; ++kt) {
            const ushort* p = agg_bf + (size_t)rr * 128 + kt * 32 + lkg * 8;
            short8 raw = *(const short8*)p;
#pragma unroll
            for (int j = 0; j < 8; ++j) {
                int k = kt * 32 + lkg * 8 + j;
                float v = bf2f((ushort)raw[j]) * scs[k] + shs[k];
                v = v > 0.f ? v : SLOPE * v;
                ushort hb = f2bf(v);
                ah[kt][j] = (short)hb;
                al[kt][j] = (short)f2bf(v - bf2f(hb));
            }
        }
        f32x4 acc[4];
#pragma unroll
        for (int ct = 0; ct < 4; ++ct) {
            float bb = bias[ct];
            acc[ct][0] = bb; acc[ct][1] = bb; acc[ct][2] = bb; acc[ct][3] = bb;
        }
#pragma unroll
        for (int kt = 0; kt < 4; ++kt) {
#pragma unroll
            for (int ct = 0; ct < 4; ++ct) {
                short8 wh = *(const short8*)&wf[kt][ct][lane][0];
                acc[ct] = __builtin_amdgcn_mfma_f32_16x16x32_bf16(ah[kt], wh, acc[ct], 0, 0, 0);
                acc[ct] = __builtin_amdgcn_mfma_f32_16x16x32_bf16(al[kt], wh, acc[ct], 0, 0, 0);
            }
        }
#pragma unroll
        for (int j = 0; j < 4; ++j) {
            float ss = acc[0][j] * acc[0][j];
#pragma unroll
            for (int ct = 1; ct < 4; ++ct) ss = fmaf(acc[ct][j], acc[ct][j], ss);
            ss += __shfl_xor(ss, 1, 64);
            ss += __shfl_xor(ss, 2, 64);
            ss += __shfl_xor(ss, 4, 64);
            ss += __shfl_xor(ss, 8, 64);
            float srow = NSCALE / fmaxf(sqrtf(ss), 1e-12f);
            int row = (int)r0 + lkg * 4 + j;
            if (row < n) {
                float dr = dinv[row];
                char* base = l_ext + (size_t)row * LSTRIDE;
#pragma unroll
                for (int ct = 0; ct < 4; ++ct)
                    *(ushort*)(base + (ct * 16 + lrow) * 2) = f2bf(acc[ct][j] * dr);
                if (lrow == 0) *(float*)(base + 128) = srow;
            }
        }
    }
}

// pull SpMM2 over l_ext (192B rows), octet-per-edge, dual accumulation, reparam.
__global__ __launch_bounds__(512) void k_spmm2_csr(const int* __restrict__ rowptr,
        const int* __restrict__ col, const char* __restrict__ lb,
        const float* __restrict__ dinv, const float* __restrict__ noise,
        float* __restrict__ mu, float* __restrict__ lsd, float* __restrict__ zeta,
        int n) {
    int node = blockIdx.x * 8 + ((int)threadIdx.x >> 6);
    if (node >= n) return;
    int lane = threadIdx.x & 63;
    int oct = lane >> 3, g = lane & 7;  // lane holds cols 8g..8g+7
    int beg = rowptr[node], end = rowptr[node + 1];
    float am[8], al[8];
#pragma unroll
    for (int j = 0; j < 8; ++j) { am[j] = 0.f; al[j] = 0.f; }
    if (oct == 0) {  // self-loop
        const char* rb = lb + (size_t)node * LSTRIDE;
        uint4 v = *(const uint4*)(rb + g * 16);
        float sv = *(const float*)(rb + 128);
        acc8(v, sv, 1.f, am, al);
    }
    int p = beg;
    for (; p + 16 <= end; p += 16) {
        int c0 = col[p + oct], c1 = col[p + 8 + oct];
        const char* r0 = lb + (size_t)c0 * LSTRIDE;
        const char* r1 = lb + (size_t)c1 * LSTRIDE;
        uint4 v0 = *(const uint4*)(r0 + g * 16);
        float s0 = *(const float*)(r0 + 128);
        uint4 v1 = *(const uint4*)(r1 + g * 16);
        float s1 = *(const float*)(r1 + 128);
        acc8(v0, s0, 1.f, am, al);
        acc8(v1, s1, 1.f, am, al);
    }
    if (p + 8 <= end) {
        int c0 = col[p + oct];
        const char* r0 = lb + (size_t)c0 * LSTRIDE;
        uint4 v0 = *(const uint4*)(r0 + g * 16);
        float s0 = *(const float*)(r0 + 128);
        acc8(v0, s0, 1.f, am, al);
        p += 8;
    }
    if (p < end) {
        int i0 = p + oct;
        int c0 = col[i0 < end ? i0 : end - 1];
        float w0 = (i0 < end) ? 1.f : 0.f;
        const char* r0 = lb + (size_t)c0 * LSTRIDE;
        uint4 v0 = *(const uint4*)(r0 + g * 16);
        float s0 = *(const float*)(r0 + 128);
        acc8(v0, s0, w0, am, al);
    }
#pragma unroll
    for (int j = 0; j < 8; ++j) {
        am[j] += __shfl_xor(am[j], 8, 64);
        am[j] += __shfl_xor(am[j], 16, 64);
        am[j] += __shfl_xor(am[j], 32, 64);
        al[j] += __shfl_xor(al[j], 8, 64);
        al[j] += __shfl_xor(al[j], 16, 64);
        al[j] += __shfl_xor(al[j], 32, 64);
    }
    if (lane < 8) {
        float di = dinv[node];
        size_t idx = (size_t)node * 64 + lane * 8;
        f32x4 m0, m1, l0, l1, z0, z1;
#pragma unroll
        for (int j = 0; j < 4; ++j) {
            m0[j] = am[j] * di;     m1[j] = am[j + 4] * di;
            l0[j] = al[j] * di;     l1[j] = al[j + 4] * di;
        }
        f32x4 n0 = *(const f32x4*)(noise + idx);
        f32x4 n1 = *(const f32x4*)(noise + idx + 4);
#pragma unroll
        for (int j = 0; j < 4; ++j) {
            z0[j] = m0[j] + n0[j] * expf(l0[j]);
            z1[j] = m1[j] + n1[j] * expf(l1[j]);
        }
        *(f32x4*)(mu + idx) = m0;   *(f32x4*)(mu + idx + 4) = m1;
        *(f32x4*)(lsd + idx) = l0;  *(f32x4*)(lsd + idx + 4) = l1;
        *(f32x4*)(zeta + idx) = z0; *(f32x4*)(zeta + idx + 4) = z1;
    }
}

extern "C" void kernel_launch(void* const* d_in, const int* in_sizes, int n_in,
                              void* d_out, int out_size, void* d_ws, size_t ws_size,
                              hipStream_t stream) {
    const float* x     = (const float*)d_in[0];
    const int*   esrc  = (const int*)d_in[1];
    const int*   edst  = (const int*)d_in[2];
    const float* W1    = (const float*)d_in[3];
    const float* b1    = (const float*)d_in[4];
    const float* gamma = (const float*)d_in[5];
    const float* beta  = (const float*)d_in[6];
    const float* Wmu   = (const float*)d_in[7];
    const float* bmu   = (const float*)d_in[8];
    const float* noise = (const float*)d_in[9];
    int N = in_sizes[0] / D_IN;
    int E = in_sizes[1];
    int B = (N + NB - 1) >> BSH;
    int nwt = (N + 15) / 16;
    int ntile = (E + T1 - 1) / T1;

    float* out  = (float*)d_out;
    float* mu   = out;
    float* lsd  = out + (size_t)N * D_OUT;
    float* zeta = out + 2 * (size_t)N * D_OUT;

    char* ws = (char*)d_ws;
    size_t off = 0;
    auto alloc = [&](size_t bytes) {
        void* p = ws + off;
        off += (bytes + 255) & ~(size_t)255;
        return p;
    };
    float* accum  = (float*)alloc(1024);
    int* bcnt     = (int*)alloc((size_t)B * 4);
    size_t zbytes = off;  // accum + bcnt zeroed
    int* bbase    = (int*)alloc(((size_t)B + 1) * 4);
    int* tailE    = (int*)alloc((size_t)B * 4);
    int* rowptr   = (int*)alloc(((size_t)N + 1) * 4);
    float* dinv   = (float*)alloc((size_t)N * 4);
    uint* ep      = (uint*)alloc((size_t)E * 4);
    int* col      = (int*)alloc((size_t)E * 4);
    ushort* h_bf  = (ushort*)alloc((size_t)N * D_HID * 2);  // two half-tables
    uint2* aggq   = (uint2*)alloc((size_t)N * D_HID * 2);
    char* l_ext   = (char*)alloc((size_t)N * LSTRIDE);

    hipMemsetAsync(d_ws, 0, zbytes, stream);

    size_t n64 = (size_t)N * 64;
    const uint2* tbl0 = (const uint2*)h_bf;
    const uint2* tbl1 = (const uint2*)(h_bf + n64);

    k_bhist<<<ntile, 256, 0, stream>>>(edst, bcnt, E, B);
    k_bscan<<<1, 512, 0, stream>>>(bcnt, bbase, tailE, B);
    k_part<<<ntile, 256, 0, stream>>>(esrc, edst, tailE, ep, E, B);
    k_csr<<<B, 256, 0, stream>>>(ep, bbase, rowptr, dinv, col, N, B);
    k_gemm1_mfma<<<512, 256, 0, stream>>>(x, W1, b1, dinv, h_bf, N, nwt);
    k_spmm1_csr<<<2048, 512, 0, stream>>>(rowptr, col, tbl0, dinv, aggq, accum, N, 0);
    k_spmm1_csr<<<2048, 512, 0, stream>>>(rowptr, col, tbl1, dinv, aggq, accum, N, 1);
    k_gemm2_mfma<<<512, 256, 0, stream>>>((const ushort*)aggq, Wmu, bmu, accum,
                                          gamma, beta, dinv, l_ext, 1.0f / (float)N, N, nwt);
    k_spmm2_csr<<<(N + 7) / 8, 512, 0, stream>>>(rowptr, col, l_ext, dinv, noise, mu, lsd, zeta, N);
}